// Round 3
// baseline (6077.822 us; speedup 1.0000x reference)
//
#include <hip/hip_runtime.h>
#include <hip/hip_bf16.h>
#include <cstdint>
#include <cstddef>

#define BROWS 64          // rows per bucket
#define KEYSHIFT 20       // col in low 20 bits, rel-row above
#define COLMASK 0xFFFFFu

// ---------------------------------------------------------------------------
// Host-side reproduction of np.random.RandomState(2).permutation(64):
// MT19937 init_genrand(2), Fisher-Yates with numpy random_interval
// (mask+rejection). Mask bit d = (perm[d] >= 38).
// ---------------------------------------------------------------------------
static uint64_t compute_mask_bits() {
    uint32_t mt[624];
    mt[0] = 2u;
    for (int i = 1; i < 624; i++)
        mt[i] = 1812433253u * (mt[i - 1] ^ (mt[i - 1] >> 30)) + (uint32_t)i;
    int mti = 624;
    auto genrand = [&]() -> uint32_t {
        if (mti >= 624) {
            for (int k = 0; k < 624; k++) {
                uint32_t y = (mt[k] & 0x80000000u) | (mt[(k + 1) % 624] & 0x7fffffffu);
                mt[k] = mt[(k + 397) % 624] ^ (y >> 1) ^ ((y & 1u) ? 2567483615u : 0u);
            }
            mti = 0;
        }
        uint32_t y = mt[mti++];
        y ^= y >> 11;
        y ^= (y << 7) & 2636928640u;
        y ^= (y << 15) & 4022730752u;
        y ^= y >> 18;
        return y;
    };
    int arr[64];
    for (int i = 0; i < 64; i++) arr[i] = i;
    for (int i = 63; i >= 1; i--) {
        uint32_t mask = (uint32_t)i;
        mask |= mask >> 1; mask |= mask >> 2; mask |= mask >> 4;
        mask |= mask >> 8; mask |= mask >> 16;
        uint32_t v;
        do { v = genrand() & mask; } while (v > (uint32_t)i);
        int tmp = arr[i]; arr[i] = arr[v]; arr[v] = tmp;
    }
    uint64_t bits = 0;
    for (int d = 0; d < 64; d++)
        if (arr[d] >= 38) bits |= (1ull << d);
    return bits;
}

// ---------------------------------------------------------------------------
// Output-row flag set: rows actually read by the final dot.
// ---------------------------------------------------------------------------
__global__ void flag_kernel(const int* __restrict__ users, const int* __restrict__ items,
                            unsigned char* __restrict__ flag, int B, int U) {
    int i = blockIdx.x * 256 + threadIdx.x;
    if (i < B) flag[users[i]] = 1;
    else if (i < 2 * B) flag[U + items[i - B]] = 1;
}

// ---------------------------------------------------------------------------
// Bucket histogram: counts per row-bucket for full list and flagged-row list.
// ---------------------------------------------------------------------------
__global__ void bucket_hist_kernel(const int* __restrict__ rows,
                                   const unsigned char* __restrict__ flag,
                                   int* __restrict__ cntA, int* __restrict__ cntF, int e) {
    int i = blockIdx.x * 256 + threadIdx.x;
    if (i >= e) return;
    int r = rows[i];
    int b = r >> 6;
    atomicAdd(&cntA[b], 1);
    if (flag[r]) atomicAdd(&cntF[b], 1);
}

// ---------------------------------------------------------------------------
// Exclusive scan of two K-length count arrays into (K+1)-length ptr arrays.
// Single block, 8 elements/thread => supports K+1 <= 2048.
// ---------------------------------------------------------------------------
__global__ void bucket_scan_kernel(const int* __restrict__ cntA, const int* __restrict__ cntF,
                                   int* __restrict__ bptr, int* __restrict__ fptr, int K) {
    __shared__ int sh[256];
    int t = threadIdx.x;
    for (int sel = 0; sel < 2; sel++) {
        const int* cnt = sel ? cntF : cntA;
        int* outp = sel ? fptr : bptr;
        int base = t * 8;
        int v[8];
        int s = 0;
        #pragma unroll
        for (int j = 0; j < 8; j++) {
            int idx = base + j;
            v[j] = (idx < K) ? cnt[idx] : 0;
            s += v[j];
        }
        sh[t] = s;
        __syncthreads();
        for (int off = 1; off < 256; off <<= 1) {
            int x = (t >= off) ? sh[t - off] : 0;
            __syncthreads();
            sh[t] += x;
            __syncthreads();
        }
        int run = sh[t] - s;
        #pragma unroll
        for (int j = 0; j < 8; j++) {
            int idx = base + j;
            if (idx <= K) outp[idx] = run;
            run += v[j];
        }
        __syncthreads();
    }
}

// ---------------------------------------------------------------------------
// Bucketed scatter: 8B packed record (rel<<20 | col, val) per edge, written at
// bucket-cursor positions (K active regions -> writes coalesce in L2).
// Flagged-row edges additionally go to a second bucketed list for layer 2.
// ---------------------------------------------------------------------------
__global__ void bucket_scatter_kernel(const int* __restrict__ rows, const int* __restrict__ cols,
                                      const float* __restrict__ vals,
                                      const unsigned char* __restrict__ flag,
                                      const int* __restrict__ bptr, const int* __restrict__ fptr,
                                      int* __restrict__ curA, int* __restrict__ curF,
                                      uint2* __restrict__ rec, uint2* __restrict__ frec,
                                      int e, int fcap) {
    int i = blockIdx.x * 256 + threadIdx.x;
    if (i >= e) return;
    int r = rows[i];
    int b = r >> 6;
    uint32_t key = ((uint32_t)(r & 63) << KEYSHIFT) | (uint32_t)cols[i];
    uint32_t vbits = __float_as_uint(vals[i]);
    int pos = bptr[b] + atomicAdd(&curA[b], 1);
    rec[pos] = make_uint2(key, vbits);
    if (flag[r]) {
        int p2 = fptr[b] + atomicAdd(&curF[b], 1);
        if (p2 < fcap) frec[p2] = make_uint2(key, vbits);
    }
}

// ---------------------------------------------------------------------------
// Per-rating MLP: h = leaky_relu(x @ W1a + c1) @ W2 + b2
// prev = h for all rows; out_acc += h only for flagged rows.
// ---------------------------------------------------------------------------
__global__ __launch_bounds__(256) void mlp_kernel(
    const float* __restrict__ user_emb, const float* __restrict__ item_emb,
    const float* __restrict__ rating_emb, const float* __restrict__ W1,
    const float* __restrict__ b1, const float* __restrict__ W2,
    const float* __restrict__ b2, float* __restrict__ prev,
    float* __restrict__ out_acc, const unsigned char* __restrict__ flag,
    int r, int n_rows, int U) {
    __shared__ float sW1[64 * 64];  // [k][j]
    __shared__ float sW2[64 * 64];  // [k][j]
    __shared__ float sXT[64 * 64];  // [k][i]
    __shared__ float sTT[64 * 64];  // [k][i]
    __shared__ float sc1[64];
    __shared__ float sb2v[64];

    int t = threadIdx.x;
    int row0 = blockIdx.x * 64;
    const float* W1r = W1 + (size_t)r * (128 * 64);
    const float* W2r = W2 + (size_t)r * (64 * 64);

    #pragma unroll
    for (int q = 0; q < 4; q++) {
        int f = t + 256 * q;
        int k = f >> 4, c = (f & 15) * 4;
        *(float4*)(sW1 + k * 64 + c) = *(const float4*)(W1r + k * 64 + c);
        *(float4*)(sW2 + k * 64 + c) = *(const float4*)(W2r + k * 64 + c);
    }
    #pragma unroll
    for (int q = 0; q < 4; q++) {
        int f = t + 256 * q;
        int i = f >> 4, c = (f & 15) * 4;
        int nrow = row0 + i;
        float4 xv = make_float4(0.f, 0.f, 0.f, 0.f);
        if (nrow < n_rows) {
            const float* src = (nrow < U) ? (user_emb + (size_t)nrow * 64)
                                          : (item_emb + (size_t)(nrow - U) * 64);
            xv = *(const float4*)(src + c);
        }
        sXT[(c + 0) * 64 + i] = xv.x;
        sXT[(c + 1) * 64 + i] = xv.y;
        sXT[(c + 2) * 64 + i] = xv.z;
        sXT[(c + 3) * 64 + i] = xv.w;
    }
    if (t < 64) {
        float acc = b1[r * 64 + t];
        for (int k = 0; k < 64; k++)
            acc += rating_emb[r * 64 + k] * W1r[(64 + k) * 64 + t];
        sc1[t] = acc;
    } else if (t < 128) {
        sb2v[t - 64] = b2[r * 64 + (t - 64)];
    }
    __syncthreads();

    int i0 = (t & 15) * 4, j0 = (t >> 4) * 4;
    float acc[4][4];
    #pragma unroll
    for (int a = 0; a < 4; a++)
        #pragma unroll
        for (int b = 0; b < 4; b++) acc[a][b] = sc1[j0 + b];
    for (int k = 0; k < 64; k++) {
        float4 xv = *(const float4*)(sXT + k * 64 + i0);
        float4 wv = *(const float4*)(sW1 + k * 64 + j0);
        float xs[4] = {xv.x, xv.y, xv.z, xv.w};
        float ws[4] = {wv.x, wv.y, wv.z, wv.w};
        #pragma unroll
        for (int a = 0; a < 4; a++)
            #pragma unroll
            for (int b = 0; b < 4; b++) acc[a][b] += xs[a] * ws[b];
    }
    #pragma unroll
    for (int a = 0; a < 4; a++)
        #pragma unroll
        for (int b = 0; b < 4; b++) {
            float v = acc[a][b];
            v = (v >= 0.f) ? v : 0.01f * v;
            sTT[(j0 + b) * 64 + (i0 + a)] = v;
        }
    __syncthreads();

    #pragma unroll
    for (int a = 0; a < 4; a++)
        #pragma unroll
        for (int b = 0; b < 4; b++) acc[a][b] = sb2v[j0 + b];
    for (int k = 0; k < 64; k++) {
        float4 xv = *(const float4*)(sTT + k * 64 + i0);
        float4 wv = *(const float4*)(sW2 + k * 64 + j0);
        float xs[4] = {xv.x, xv.y, xv.z, xv.w};
        float ws[4] = {wv.x, wv.y, wv.z, wv.w};
        #pragma unroll
        for (int a = 0; a < 4; a++)
            #pragma unroll
            for (int b = 0; b < 4; b++) acc[a][b] += xs[a] * ws[b];
    }
    #pragma unroll
    for (int a = 0; a < 4; a++) {
        int nrow = row0 + i0 + a;
        if (nrow < n_rows) {
            float4 hv = make_float4(acc[a][0], acc[a][1], acc[a][2], acc[a][3]);
            *(float4*)(prev + (size_t)nrow * 64 + j0) = hv;
            if (flag[nrow]) {
                float4 ov = *(const float4*)(out_acc + (size_t)nrow * 64 + j0);
                ov.x += hv.x; ov.y += hv.y; ov.z += hv.z; ov.w += hv.w;
                *(float4*)(out_acc + (size_t)nrow * 64 + j0) = ov;
            }
        }
    }
}

// ---------------------------------------------------------------------------
// Bucketed LDS-accumulator SpMM (layers 0/1): one block per 64-row bucket,
// 16KB LDS f32 accumulator, wave-per-edge gather + ds_add_f32 per lane.
// Epilogue: next = agg (contiguous), out_acc += agg for flagged rows.
// ---------------------------------------------------------------------------
__global__ __launch_bounds__(256) void spmm_lds_kernel(
    const float* __restrict__ prev, float* __restrict__ next,
    float* __restrict__ out_acc, const int* __restrict__ bptr,
    const uint2* __restrict__ rec, const unsigned char* __restrict__ flag, int n) {
    __shared__ float acc[BROWS * 64];
    int t = threadIdx.x;
    int b = blockIdx.x;
    int wid = t >> 6, lane = t & 63;

    #pragma unroll
    for (int j = 0; j < BROWS * 64 / 256; j++) acc[t + j * 256] = 0.f;
    __syncthreads();

    int start = bptr[b], end = bptr[b + 1];
    int cnt = end - start;
    int chunk = (cnt + 3) >> 2;
    int ws = start + wid * chunk;
    int we = ws + chunk;
    if (we > end) we = end;
    int e = ws;
    for (; e + 3 < we; e += 4) {
        uint2 r0 = rec[e + 0], r1 = rec[e + 1], r2 = rec[e + 2], r3 = rec[e + 3];
        float p0 = prev[(size_t)(r0.x & COLMASK) * 64 + lane];
        float p1 = prev[(size_t)(r1.x & COLMASK) * 64 + lane];
        float p2 = prev[(size_t)(r2.x & COLMASK) * 64 + lane];
        float p3 = prev[(size_t)(r3.x & COLMASK) * 64 + lane];
        atomicAdd(&acc[(r0.x >> KEYSHIFT) * 64 + lane], __uint_as_float(r0.y) * p0);
        atomicAdd(&acc[(r1.x >> KEYSHIFT) * 64 + lane], __uint_as_float(r1.y) * p1);
        atomicAdd(&acc[(r2.x >> KEYSHIFT) * 64 + lane], __uint_as_float(r2.y) * p2);
        atomicAdd(&acc[(r3.x >> KEYSHIFT) * 64 + lane], __uint_as_float(r3.y) * p3);
    }
    for (; e < we; e++) {
        uint2 r0 = rec[e];
        float p0 = prev[(size_t)(r0.x & COLMASK) * 64 + lane];
        atomicAdd(&acc[(r0.x >> KEYSHIFT) * 64 + lane], __uint_as_float(r0.y) * p0);
    }
    __syncthreads();

    int row0 = b * BROWS;
    #pragma unroll
    for (int j = 0; j < BROWS / 4; j++) {
        int rr = wid * (BROWS / 4) + j;
        int row = row0 + rr;
        if (row < n) {
            float agg = acc[rr * 64 + lane];
            next[(size_t)row * 64 + lane] = agg;
            if (flag[row]) out_acc[(size_t)row * 64 + lane] += agg;
        }
    }
}

// ---------------------------------------------------------------------------
// Layer-2 (masked, pruned) SpMM over the flagged-row edge list. Writes only
// out_acc for flagged rows: res = maskbit ? agg : prev[row].
// ---------------------------------------------------------------------------
__global__ __launch_bounds__(256) void spmm_lds_masked_kernel(
    const float* __restrict__ prev, float* __restrict__ out_acc,
    const int* __restrict__ fptr, const uint2* __restrict__ frec,
    const unsigned char* __restrict__ flag, unsigned long long maskbits, int n) {
    __shared__ float acc[BROWS * 64];
    int t = threadIdx.x;
    int b = blockIdx.x;
    int wid = t >> 6, lane = t & 63;

    #pragma unroll
    for (int j = 0; j < BROWS * 64 / 256; j++) acc[t + j * 256] = 0.f;
    __syncthreads();

    int start = fptr[b], end = fptr[b + 1];
    int cnt = end - start;
    int chunk = (cnt + 3) >> 2;
    int ws = start + wid * chunk;
    int we = ws + chunk;
    if (we > end) we = end;
    int e = ws;
    for (; e + 3 < we; e += 4) {
        uint2 r0 = frec[e + 0], r1 = frec[e + 1], r2 = frec[e + 2], r3 = frec[e + 3];
        float p0 = prev[(size_t)(r0.x & COLMASK) * 64 + lane];
        float p1 = prev[(size_t)(r1.x & COLMASK) * 64 + lane];
        float p2 = prev[(size_t)(r2.x & COLMASK) * 64 + lane];
        float p3 = prev[(size_t)(r3.x & COLMASK) * 64 + lane];
        atomicAdd(&acc[(r0.x >> KEYSHIFT) * 64 + lane], __uint_as_float(r0.y) * p0);
        atomicAdd(&acc[(r1.x >> KEYSHIFT) * 64 + lane], __uint_as_float(r1.y) * p1);
        atomicAdd(&acc[(r2.x >> KEYSHIFT) * 64 + lane], __uint_as_float(r2.y) * p2);
        atomicAdd(&acc[(r3.x >> KEYSHIFT) * 64 + lane], __uint_as_float(r3.y) * p3);
    }
    for (; e < we; e++) {
        uint2 r0 = frec[e];
        float p0 = prev[(size_t)(r0.x & COLMASK) * 64 + lane];
        atomicAdd(&acc[(r0.x >> KEYSHIFT) * 64 + lane], __uint_as_float(r0.y) * p0);
    }
    __syncthreads();

    int keep = (int)((maskbits >> lane) & 1ull);
    int row0 = b * BROWS;
    #pragma unroll
    for (int j = 0; j < BROWS / 4; j++) {
        int rr = wid * (BROWS / 4) + j;
        int row = row0 + rr;
        if (row < n && flag[row]) {
            float agg = acc[rr * 64 + lane];
            float pv = prev[(size_t)row * 64 + lane];
            float res = keep ? agg : pv;
            out_acc[(size_t)row * 64 + lane] += res;
        }
    }
}

// ---------------------------------------------------------------------------
// Final: out[b] = (1/R^2) * dot(out_acc[users[b]], out_acc[U+items[b]])
// ---------------------------------------------------------------------------
__global__ __launch_bounds__(256) void dot_kernel(
    const float* __restrict__ out_acc, const int* __restrict__ users,
    const int* __restrict__ items, float* __restrict__ out,
    int Bn, int U, float scale) {
    int w = (int)((blockIdx.x * (unsigned)blockDim.x + threadIdx.x) >> 6);
    int lane = threadIdx.x & 63;
    if (w >= Bn) return;
    int u = users[w], it = items[w];
    float a = out_acc[(size_t)u * 64 + lane];
    float c = out_acc[((size_t)(U + it)) * 64 + lane];
    float p = a * c;
    #pragma unroll
    for (int off = 32; off > 0; off >>= 1) p += __shfl_down(p, off);
    if (lane == 0) out[w] = p * scale;
}

// ---------------------------------------------------------------------------
extern "C" void kernel_launch(void* const* d_in, const int* in_sizes, int n_in,
                              void* d_out, int out_size, void* d_ws, size_t ws_size,
                              hipStream_t stream) {
    const int* users = (const int*)d_in[0];
    const int* items = (const int*)d_in[1];
    const float* user_emb = (const float*)d_in[2];
    const float* item_emb = (const float*)d_in[3];
    const float* rating_emb = (const float*)d_in[4];
    const float* W1 = (const float*)d_in[5];
    const float* b1 = (const float*)d_in[6];
    const float* W2 = (const float*)d_in[7];
    const float* b2 = (const float*)d_in[8];
    const int* rows = (const int*)d_in[9];
    const int* cols = (const int*)d_in[10];
    const float* vals = (const float*)d_in[11];
    float* out = (float*)d_out;

    const int Dd = 64;
    int U = in_sizes[2] / Dd;
    int I = in_sizes[3] / Dd;
    int R = in_sizes[4] / Dd;
    int N = U + I;
    int E = in_sizes[9] / R;
    int Bn = in_sizes[0];
    int K = (N + BROWS - 1) / BROWS;   // row buckets; K+1 must be <= 2048
    int fcap = E / 2;

    char* p = (char*)d_ws;
    auto carve = [&](size_t bytes) -> char* {
        char* q = p;
        p += (bytes + 255) & ~(size_t)255;
        return q;
    };
    float* out_acc = (float*)carve((size_t)N * 64 * 4);
    float* bufA = (float*)carve((size_t)N * 64 * 4);
    float* bufB = (float*)carve((size_t)N * 64 * 4);
    uint2* rec = (uint2*)carve((size_t)E * 8);
    uint2* frec = (uint2*)carve((size_t)fcap * 8);
    int* scratch4 = (int*)carve((size_t)4 * K * 4);  // cntA,cntF,curA,curF
    int* cntA = scratch4;
    int* cntF = scratch4 + K;
    int* curA = scratch4 + 2 * K;
    int* curF = scratch4 + 3 * K;
    int* bptr = (int*)carve((size_t)(K + 1) * 4);
    int* fptr = (int*)carve((size_t)(K + 1) * 4);
    unsigned char* flag = (unsigned char*)carve((size_t)N);

    uint64_t maskbits = compute_mask_bits();

    hipMemsetAsync(out_acc, 0, (size_t)N * 64 * 4, stream);
    hipMemsetAsync(flag, 0, (size_t)N, stream);

    flag_kernel<<<(2 * Bn + 255) / 256, 256, 0, stream>>>(users, items, flag, Bn, U);

    int eblocks = (E + 255) / 256;
    for (int r = 0; r < R; r++) {
        const int* rows_r = rows + (size_t)r * E;
        const int* cols_r = cols + (size_t)r * E;
        const float* vals_r = vals + (size_t)r * E;

        hipMemsetAsync(scratch4, 0, (size_t)4 * K * 4, stream);
        bucket_hist_kernel<<<eblocks, 256, 0, stream>>>(rows_r, flag, cntA, cntF, E);
        bucket_scan_kernel<<<1, 256, 0, stream>>>(cntA, cntF, bptr, fptr, K);
        bucket_scatter_kernel<<<eblocks, 256, 0, stream>>>(rows_r, cols_r, vals_r, flag,
                                                           bptr, fptr, curA, curF,
                                                           rec, frec, E, fcap);

        mlp_kernel<<<(N + 63) / 64, 256, 0, stream>>>(user_emb, item_emb, rating_emb,
                                                      W1, b1, W2, b2, bufA, out_acc,
                                                      flag, r, N, U);

        spmm_lds_kernel<<<K, 256, 0, stream>>>(bufA, bufB, out_acc, bptr, rec, flag, N);
        spmm_lds_kernel<<<K, 256, 0, stream>>>(bufB, bufA, out_acc, bptr, rec, flag, N);
        spmm_lds_masked_kernel<<<K, 256, 0, stream>>>(bufA, out_acc, fptr, frec, flag,
                                                      maskbits, N);
    }

    float scale = 1.0f / (float)(R * R);
    dot_kernel<<<(Bn * 64 + 255) / 256, 256, 0, stream>>>(out_acc, users, items, out,
                                                          Bn, U, scale);
}

// Round 4
// 2557.326 us; speedup vs baseline: 2.3766x; 2.3766x over previous
//
#include <hip/hip_runtime.h>
#include <hip/hip_bf16.h>
#include <cstdint>
#include <cstddef>

#define BROWS 64          // rows per bucket
#define KEYSHIFT 20       // col in low 20 bits, rel-row above
#define COLMASK 0xFFFFFu

// ---------------------------------------------------------------------------
// Host-side reproduction of np.random.RandomState(2).permutation(64):
// MT19937 init_genrand(2), Fisher-Yates with numpy random_interval
// (mask+rejection). Mask bit d = (perm[d] >= 38).
// ---------------------------------------------------------------------------
static uint64_t compute_mask_bits() {
    uint32_t mt[624];
    mt[0] = 2u;
    for (int i = 1; i < 624; i++)
        mt[i] = 1812433253u * (mt[i - 1] ^ (mt[i - 1] >> 30)) + (uint32_t)i;
    int mti = 624;
    auto genrand = [&]() -> uint32_t {
        if (mti >= 624) {
            for (int k = 0; k < 624; k++) {
                uint32_t y = (mt[k] & 0x80000000u) | (mt[(k + 1) % 624] & 0x7fffffffu);
                mt[k] = mt[(k + 397) % 624] ^ (y >> 1) ^ ((y & 1u) ? 2567483615u : 0u);
            }
            mti = 0;
        }
        uint32_t y = mt[mti++];
        y ^= y >> 11;
        y ^= (y << 7) & 2636928640u;
        y ^= (y << 15) & 4022730752u;
        y ^= y >> 18;
        return y;
    };
    int arr[64];
    for (int i = 0; i < 64; i++) arr[i] = i;
    for (int i = 63; i >= 1; i--) {
        uint32_t mask = (uint32_t)i;
        mask |= mask >> 1; mask |= mask >> 2; mask |= mask >> 4;
        mask |= mask >> 8; mask |= mask >> 16;
        uint32_t v;
        do { v = genrand() & mask; } while (v > (uint32_t)i);
        int tmp = arr[i]; arr[i] = arr[v]; arr[v] = tmp;
    }
    uint64_t bits = 0;
    for (int d = 0; d < 64; d++)
        if (arr[d] >= 38) bits |= (1ull << d);
    return bits;
}

// ---------------------------------------------------------------------------
// Output-row flag set + compacted list (rows read by the final dot).
// ---------------------------------------------------------------------------
__global__ void flag_kernel(const int* __restrict__ users, const int* __restrict__ items,
                            unsigned char* __restrict__ flag, int B, int U) {
    int i = blockIdx.x * 256 + threadIdx.x;
    if (i < B) flag[users[i]] = 1;
    else if (i < 2 * B) flag[U + items[i - B]] = 1;
}

__global__ void flist_kernel(const unsigned char* __restrict__ flag,
                             int* __restrict__ flist, int* __restrict__ fcount, int n) {
    int i = blockIdx.x * 256 + threadIdx.x;
    if (i < n && flag[i]) {
        int p = atomicAdd(fcount, 1);
        flist[p] = i;
    }
}

// ---------------------------------------------------------------------------
// Bucket histogram over row>>6 (K counters).
// ---------------------------------------------------------------------------
__global__ void bucket_hist_kernel(const int* __restrict__ rows,
                                   int* __restrict__ cntA, int e) {
    int i = blockIdx.x * 256 + threadIdx.x;
    if (i >= e) return;
    atomicAdd(&cntA[rows[i] >> 6], 1);
}

// ---------------------------------------------------------------------------
// Exclusive scan of K bucket counts -> bptr[K+1]. Single block, K+1 <= 2048.
// ---------------------------------------------------------------------------
__global__ void bucket_scan_kernel(const int* __restrict__ cntA,
                                   int* __restrict__ bptr, int K) {
    __shared__ int sh[256];
    int t = threadIdx.x;
    int base = t * 8;
    int v[8];
    int s = 0;
    #pragma unroll
    for (int j = 0; j < 8; j++) {
        int idx = base + j;
        v[j] = (idx < K) ? cntA[idx] : 0;
        s += v[j];
    }
    sh[t] = s;
    __syncthreads();
    for (int off = 1; off < 256; off <<= 1) {
        int x = (t >= off) ? sh[t - off] : 0;
        __syncthreads();
        sh[t] += x;
        __syncthreads();
    }
    int run = sh[t] - s;
    #pragma unroll
    for (int j = 0; j < 8; j++) {
        int idx = base + j;
        if (idx <= K) bptr[idx] = run;
        run += v[j];
    }
}

// ---------------------------------------------------------------------------
// Bucketed scatter: 8B packed record (rel<<20 | col, val) written at
// bucket-cursor positions -> only K active write regions (L2-friendly).
// ---------------------------------------------------------------------------
__global__ void bucket_scatter_kernel(const int* __restrict__ rows, const int* __restrict__ cols,
                                      const float* __restrict__ vals,
                                      const int* __restrict__ bptr, int* __restrict__ curA,
                                      uint2* __restrict__ rec, int e) {
    int i = blockIdx.x * 256 + threadIdx.x;
    if (i >= e) return;
    int r = rows[i];
    int b = r >> 6;
    uint32_t key = ((uint32_t)(r & 63) << KEYSHIFT) | (uint32_t)cols[i];
    int pos = bptr[b] + atomicAdd(&curA[b], 1);
    rec[pos] = make_uint2(key, __float_as_uint(vals[i]));
}

// ---------------------------------------------------------------------------
// Per-bucket counting sort by rel-row: rec -> srec (row-sorted), emits
// row_ptr for the bucket's 64 rows. One block per bucket.
// ---------------------------------------------------------------------------
__global__ __launch_bounds__(256) void bucket_sort_kernel(
    const uint2* __restrict__ rec, uint2* __restrict__ srec,
    const int* __restrict__ bptr, int* __restrict__ row_ptr, int K, int Etot) {
    __shared__ int hist[64];
    __shared__ int excl[64];
    int b = blockIdx.x;
    int t = threadIdx.x;
    if (t < 64) hist[t] = 0;
    __syncthreads();
    int start = bptr[b], end = bptr[b + 1];
    for (int e = start + t; e < end; e += 256) {
        uint2 r = rec[e];
        atomicAdd(&hist[r.x >> KEYSHIFT], 1);
    }
    __syncthreads();
    if (t == 0) {
        int run = 0;
        #pragma unroll
        for (int i = 0; i < 64; i++) { excl[i] = run; run += hist[i]; }
    }
    __syncthreads();
    if (t < 64) {
        row_ptr[b * 64 + t] = start + excl[t];
        hist[t] = 0;  // reuse as cursors
    }
    if (b == 0 && t == 0) row_ptr[K * 64] = Etot;
    __syncthreads();
    for (int e = start + t; e < end; e += 256) {
        uint2 r = rec[e];
        int rel = (int)(r.x >> KEYSHIFT);
        int pos = start + excl[rel] + atomicAdd(&hist[rel], 1);
        srec[pos] = r;
    }
}

// ---------------------------------------------------------------------------
// Per-rating MLP: h = leaky_relu(x @ W1a + c1) @ W2 + b2
// prev = h for all rows; out_acc += h only for flagged rows.
// ---------------------------------------------------------------------------
__global__ __launch_bounds__(256) void mlp_kernel(
    const float* __restrict__ user_emb, const float* __restrict__ item_emb,
    const float* __restrict__ rating_emb, const float* __restrict__ W1,
    const float* __restrict__ b1, const float* __restrict__ W2,
    const float* __restrict__ b2, float* __restrict__ prev,
    float* __restrict__ out_acc, const unsigned char* __restrict__ flag,
    int r, int n_rows, int U) {
    __shared__ float sW1[64 * 64];  // [k][j]
    __shared__ float sW2[64 * 64];  // [k][j]
    __shared__ float sXT[64 * 64];  // [k][i]
    __shared__ float sTT[64 * 64];  // [k][i]
    __shared__ float sc1[64];
    __shared__ float sb2v[64];

    int t = threadIdx.x;
    int row0 = blockIdx.x * 64;
    const float* W1r = W1 + (size_t)r * (128 * 64);
    const float* W2r = W2 + (size_t)r * (64 * 64);

    #pragma unroll
    for (int q = 0; q < 4; q++) {
        int f = t + 256 * q;
        int k = f >> 4, c = (f & 15) * 4;
        *(float4*)(sW1 + k * 64 + c) = *(const float4*)(W1r + k * 64 + c);
        *(float4*)(sW2 + k * 64 + c) = *(const float4*)(W2r + k * 64 + c);
    }
    #pragma unroll
    for (int q = 0; q < 4; q++) {
        int f = t + 256 * q;
        int i = f >> 4, c = (f & 15) * 4;
        int nrow = row0 + i;
        float4 xv = make_float4(0.f, 0.f, 0.f, 0.f);
        if (nrow < n_rows) {
            const float* src = (nrow < U) ? (user_emb + (size_t)nrow * 64)
                                          : (item_emb + (size_t)(nrow - U) * 64);
            xv = *(const float4*)(src + c);
        }
        sXT[(c + 0) * 64 + i] = xv.x;
        sXT[(c + 1) * 64 + i] = xv.y;
        sXT[(c + 2) * 64 + i] = xv.z;
        sXT[(c + 3) * 64 + i] = xv.w;
    }
    if (t < 64) {
        float acc = b1[r * 64 + t];
        for (int k = 0; k < 64; k++)
            acc += rating_emb[r * 64 + k] * W1r[(64 + k) * 64 + t];
        sc1[t] = acc;
    } else if (t < 128) {
        sb2v[t - 64] = b2[r * 64 + (t - 64)];
    }
    __syncthreads();

    int i0 = (t & 15) * 4, j0 = (t >> 4) * 4;
    float acc[4][4];
    #pragma unroll
    for (int a = 0; a < 4; a++)
        #pragma unroll
        for (int b = 0; b < 4; b++) acc[a][b] = sc1[j0 + b];
    for (int k = 0; k < 64; k++) {
        float4 xv = *(const float4*)(sXT + k * 64 + i0);
        float4 wv = *(const float4*)(sW1 + k * 64 + j0);
        float xs[4] = {xv.x, xv.y, xv.z, xv.w};
        float ws[4] = {wv.x, wv.y, wv.z, wv.w};
        #pragma unroll
        for (int a = 0; a < 4; a++)
            #pragma unroll
            for (int b = 0; b < 4; b++) acc[a][b] += xs[a] * ws[b];
    }
    #pragma unroll
    for (int a = 0; a < 4; a++)
        #pragma unroll
        for (int b = 0; b < 4; b++) {
            float v = acc[a][b];
            v = (v >= 0.f) ? v : 0.01f * v;
            sTT[(j0 + b) * 64 + (i0 + a)] = v;
        }
    __syncthreads();

    #pragma unroll
    for (int a = 0; a < 4; a++)
        #pragma unroll
        for (int b = 0; b < 4; b++) acc[a][b] = sb2v[j0 + b];
    for (int k = 0; k < 64; k++) {
        float4 xv = *(const float4*)(sTT + k * 64 + i0);
        float4 wv = *(const float4*)(sW2 + k * 64 + j0);
        float xs[4] = {xv.x, xv.y, xv.z, xv.w};
        float ws[4] = {wv.x, wv.y, wv.z, wv.w};
        #pragma unroll
        for (int a = 0; a < 4; a++)
            #pragma unroll
            for (int b = 0; b < 4; b++) acc[a][b] += xs[a] * ws[b];
    }
    #pragma unroll
    for (int a = 0; a < 4; a++) {
        int nrow = row0 + i0 + a;
        if (nrow < n_rows) {
            float4 hv = make_float4(acc[a][0], acc[a][1], acc[a][2], acc[a][3]);
            *(float4*)(prev + (size_t)nrow * 64 + j0) = hv;
            if (flag[nrow]) {
                float4 ov = *(const float4*)(out_acc + (size_t)nrow * 64 + j0);
                ov.x += hv.x; ov.y += hv.y; ov.z += hv.z; ov.w += hv.w;
                *(float4*)(out_acc + (size_t)nrow * 64 + j0) = ov;
            }
        }
    }
}

// ---------------------------------------------------------------------------
// Gather-SpMM (layers 0/1): one wave per row, lane = dim, 8x/4x unrolled edge
// loop for MLP. out_acc += only for flagged rows. Records are (key,val) uint2.
// ---------------------------------------------------------------------------
__global__ __launch_bounds__(256) void spmm_kernel(
    const float* __restrict__ prev, float* __restrict__ next,
    float* __restrict__ out_acc, const int* __restrict__ row_ptr,
    const uint2* __restrict__ srec, const unsigned char* __restrict__ flag, int n) {
    int wave = (int)((blockIdx.x * (unsigned)blockDim.x + threadIdx.x) >> 6);
    int lane = threadIdx.x & 63;
    if (wave >= n) return;
    int s = row_ptr[wave], e2 = row_ptr[wave + 1];
    float acc = 0.f;
    int e = s;
    for (; e + 7 < e2; e += 8) {
        uint2 r0 = srec[e + 0], r1 = srec[e + 1], r2 = srec[e + 2], r3 = srec[e + 3];
        uint2 r4 = srec[e + 4], r5 = srec[e + 5], r6 = srec[e + 6], r7 = srec[e + 7];
        float p0 = prev[(size_t)(r0.x & COLMASK) * 64 + lane];
        float p1 = prev[(size_t)(r1.x & COLMASK) * 64 + lane];
        float p2 = prev[(size_t)(r2.x & COLMASK) * 64 + lane];
        float p3 = prev[(size_t)(r3.x & COLMASK) * 64 + lane];
        float p4 = prev[(size_t)(r4.x & COLMASK) * 64 + lane];
        float p5 = prev[(size_t)(r5.x & COLMASK) * 64 + lane];
        float p6 = prev[(size_t)(r6.x & COLMASK) * 64 + lane];
        float p7 = prev[(size_t)(r7.x & COLMASK) * 64 + lane];
        acc += __uint_as_float(r0.y) * p0; acc += __uint_as_float(r1.y) * p1;
        acc += __uint_as_float(r2.y) * p2; acc += __uint_as_float(r3.y) * p3;
        acc += __uint_as_float(r4.y) * p4; acc += __uint_as_float(r5.y) * p5;
        acc += __uint_as_float(r6.y) * p6; acc += __uint_as_float(r7.y) * p7;
    }
    for (; e + 3 < e2; e += 4) {
        uint2 r0 = srec[e + 0], r1 = srec[e + 1], r2 = srec[e + 2], r3 = srec[e + 3];
        float p0 = prev[(size_t)(r0.x & COLMASK) * 64 + lane];
        float p1 = prev[(size_t)(r1.x & COLMASK) * 64 + lane];
        float p2 = prev[(size_t)(r2.x & COLMASK) * 64 + lane];
        float p3 = prev[(size_t)(r3.x & COLMASK) * 64 + lane];
        acc += __uint_as_float(r0.y) * p0; acc += __uint_as_float(r1.y) * p1;
        acc += __uint_as_float(r2.y) * p2; acc += __uint_as_float(r3.y) * p3;
    }
    for (; e < e2; e++) {
        uint2 r0 = srec[e];
        acc += __uint_as_float(r0.y) * prev[(size_t)(r0.x & COLMASK) * 64 + lane];
    }
    next[(size_t)wave * 64 + lane] = acc;
    if (flag[wave]) out_acc[(size_t)wave * 64 + lane] += acc;
}

// ---------------------------------------------------------------------------
// Layer-2 (masked) SpMM: only rows in flist (rows the final dot reads).
// ---------------------------------------------------------------------------
__global__ __launch_bounds__(256) void spmm_masked_kernel(
    const float* __restrict__ prev, float* __restrict__ out_acc,
    const int* __restrict__ row_ptr, const uint2* __restrict__ srec,
    unsigned long long maskbits, const int* __restrict__ flist,
    const int* __restrict__ fcount) {
    int w = (int)((blockIdx.x * (unsigned)blockDim.x + threadIdx.x) >> 6);
    int lane = threadIdx.x & 63;
    if (w >= *fcount) return;
    int row = flist[w];
    int s = row_ptr[row], e2 = row_ptr[row + 1];
    float acc = 0.f;
    int e = s;
    for (; e + 7 < e2; e += 8) {
        uint2 r0 = srec[e + 0], r1 = srec[e + 1], r2 = srec[e + 2], r3 = srec[e + 3];
        uint2 r4 = srec[e + 4], r5 = srec[e + 5], r6 = srec[e + 6], r7 = srec[e + 7];
        float p0 = prev[(size_t)(r0.x & COLMASK) * 64 + lane];
        float p1 = prev[(size_t)(r1.x & COLMASK) * 64 + lane];
        float p2 = prev[(size_t)(r2.x & COLMASK) * 64 + lane];
        float p3 = prev[(size_t)(r3.x & COLMASK) * 64 + lane];
        float p4 = prev[(size_t)(r4.x & COLMASK) * 64 + lane];
        float p5 = prev[(size_t)(r5.x & COLMASK) * 64 + lane];
        float p6 = prev[(size_t)(r6.x & COLMASK) * 64 + lane];
        float p7 = prev[(size_t)(r7.x & COLMASK) * 64 + lane];
        acc += __uint_as_float(r0.y) * p0; acc += __uint_as_float(r1.y) * p1;
        acc += __uint_as_float(r2.y) * p2; acc += __uint_as_float(r3.y) * p3;
        acc += __uint_as_float(r4.y) * p4; acc += __uint_as_float(r5.y) * p5;
        acc += __uint_as_float(r6.y) * p6; acc += __uint_as_float(r7.y) * p7;
    }
    for (; e + 3 < e2; e += 4) {
        uint2 r0 = srec[e + 0], r1 = srec[e + 1], r2 = srec[e + 2], r3 = srec[e + 3];
        float p0 = prev[(size_t)(r0.x & COLMASK) * 64 + lane];
        float p1 = prev[(size_t)(r1.x & COLMASK) * 64 + lane];
        float p2 = prev[(size_t)(r2.x & COLMASK) * 64 + lane];
        float p3 = prev[(size_t)(r3.x & COLMASK) * 64 + lane];
        acc += __uint_as_float(r0.y) * p0; acc += __uint_as_float(r1.y) * p1;
        acc += __uint_as_float(r2.y) * p2; acc += __uint_as_float(r3.y) * p3;
    }
    for (; e < e2; e++) {
        uint2 r0 = srec[e];
        acc += __uint_as_float(r0.y) * prev[(size_t)(r0.x & COLMASK) * 64 + lane];
    }
    float pv = prev[(size_t)row * 64 + lane];
    float res = ((maskbits >> lane) & 1ull) ? acc : pv;
    out_acc[(size_t)row * 64 + lane] += res;
}

// ---------------------------------------------------------------------------
// Final: out[b] = (1/R^2) * dot(out_acc[users[b]], out_acc[U+items[b]])
// ---------------------------------------------------------------------------
__global__ __launch_bounds__(256) void dot_kernel(
    const float* __restrict__ out_acc, const int* __restrict__ users,
    const int* __restrict__ items, float* __restrict__ out,
    int Bn, int U, float scale) {
    int w = (int)((blockIdx.x * (unsigned)blockDim.x + threadIdx.x) >> 6);
    int lane = threadIdx.x & 63;
    if (w >= Bn) return;
    int u = users[w], it = items[w];
    float a = out_acc[(size_t)u * 64 + lane];
    float c = out_acc[((size_t)(U + it)) * 64 + lane];
    float p = a * c;
    #pragma unroll
    for (int off = 32; off > 0; off >>= 1) p += __shfl_down(p, off);
    if (lane == 0) out[w] = p * scale;
}

// ---------------------------------------------------------------------------
extern "C" void kernel_launch(void* const* d_in, const int* in_sizes, int n_in,
                              void* d_out, int out_size, void* d_ws, size_t ws_size,
                              hipStream_t stream) {
    const int* users = (const int*)d_in[0];
    const int* items = (const int*)d_in[1];
    const float* user_emb = (const float*)d_in[2];
    const float* item_emb = (const float*)d_in[3];
    const float* rating_emb = (const float*)d_in[4];
    const float* W1 = (const float*)d_in[5];
    const float* b1 = (const float*)d_in[6];
    const float* W2 = (const float*)d_in[7];
    const float* b2 = (const float*)d_in[8];
    const int* rows = (const int*)d_in[9];
    const int* cols = (const int*)d_in[10];
    const float* vals = (const float*)d_in[11];
    float* out = (float*)d_out;

    const int Dd = 64;
    int U = in_sizes[2] / Dd;
    int I = in_sizes[3] / Dd;
    int R = in_sizes[4] / Dd;
    int N = U + I;
    int E = in_sizes[9] / R;
    int Bn = in_sizes[0];
    int K = (N + BROWS - 1) / BROWS;   // row buckets; K+1 <= 2048

    char* p = (char*)d_ws;
    auto carve = [&](size_t bytes) -> char* {
        char* q = p;
        p += (bytes + 255) & ~(size_t)255;
        return q;
    };
    float* out_acc = (float*)carve((size_t)N * 64 * 4);
    float* bufA = (float*)carve((size_t)N * 64 * 4);
    float* bufB = (float*)carve((size_t)N * 64 * 4);
    uint2* rec = (uint2*)carve((size_t)E * 8);
    uint2* srec = (uint2*)carve((size_t)E * 8);
    int* cntA = (int*)carve((size_t)K * 4);
    int* curA = (int*)carve((size_t)K * 4);
    int* bptr = (int*)carve((size_t)(K + 1) * 4);
    int* row_ptr = (int*)carve(((size_t)K * 64 + 1) * 4);
    unsigned char* flag = (unsigned char*)carve((size_t)N);
    int* flist = (int*)carve((size_t)2 * Bn * 4);
    int* fcount = (int*)carve(4);

    uint64_t maskbits = compute_mask_bits();

    hipMemsetAsync(out_acc, 0, (size_t)N * 64 * 4, stream);
    hipMemsetAsync(flag, 0, (size_t)N, stream);
    hipMemsetAsync(fcount, 0, 4, stream);

    flag_kernel<<<(2 * Bn + 255) / 256, 256, 0, stream>>>(users, items, flag, Bn, U);
    flist_kernel<<<(N + 255) / 256, 256, 0, stream>>>(flag, flist, fcount, N);

    int eblocks = (E + 255) / 256;
    int spmm_blocks = (N + 3) / 4;
    int masked_blocks = (2 * Bn + 3) / 4;  // upper bound on |flist| waves
    for (int r = 0; r < R; r++) {
        const int* rows_r = rows + (size_t)r * E;
        const int* cols_r = cols + (size_t)r * E;
        const float* vals_r = vals + (size_t)r * E;

        hipMemsetAsync(cntA, 0, (size_t)K * 4, stream);
        hipMemsetAsync(curA, 0, (size_t)K * 4, stream);
        bucket_hist_kernel<<<eblocks, 256, 0, stream>>>(rows_r, cntA, E);
        bucket_scan_kernel<<<1, 256, 0, stream>>>(cntA, bptr, K);
        bucket_scatter_kernel<<<eblocks, 256, 0, stream>>>(rows_r, cols_r, vals_r,
                                                           bptr, curA, rec, E);
        bucket_sort_kernel<<<K, 256, 0, stream>>>(rec, srec, bptr, row_ptr, K, E);

        mlp_kernel<<<(N + 63) / 64, 256, 0, stream>>>(user_emb, item_emb, rating_emb,
                                                      W1, b1, W2, b2, bufA, out_acc,
                                                      flag, r, N, U);

        spmm_kernel<<<spmm_blocks, 256, 0, stream>>>(bufA, bufB, out_acc, row_ptr,
                                                     srec, flag, N);
        spmm_kernel<<<spmm_blocks, 256, 0, stream>>>(bufB, bufA, out_acc, row_ptr,
                                                     srec, flag, N);
        spmm_masked_kernel<<<masked_blocks, 256, 0, stream>>>(bufA, out_acc, row_ptr,
                                                              srec, maskbits,
                                                              flist, fcount);
    }

    float scale = 1.0f / (float)(R * R);
    dot_kernel<<<(Bn * 64 + 255) / 256, 256, 0, stream>>>(out_acc, users, items, out,
                                                          Bn, U, scale);
}

// Round 5
// 1495.108 us; speedup vs baseline: 4.0651x; 1.7105x over previous
//
#include <hip/hip_runtime.h>
#include <hip/hip_bf16.h>
#include <cstdint>
#include <cstddef>

// ---------------------------------------------------------------------------
// Host-side reproduction of np.random.RandomState(2).permutation(64):
// MT19937 init_genrand(2), Fisher-Yates with numpy random_interval
// (mask+rejection). Mask bit d = (perm[d] >= 38).
// ---------------------------------------------------------------------------
static uint64_t compute_mask_bits() {
    uint32_t mt[624];
    mt[0] = 2u;
    for (int i = 1; i < 624; i++)
        mt[i] = 1812433253u * (mt[i - 1] ^ (mt[i - 1] >> 30)) + (uint32_t)i;
    int mti = 624;
    auto genrand = [&]() -> uint32_t {
        if (mti >= 624) {
            for (int k = 0; k < 624; k++) {
                uint32_t y = (mt[k] & 0x80000000u) | (mt[(k + 1) % 624] & 0x7fffffffu);
                mt[k] = mt[(k + 397) % 624] ^ (y >> 1) ^ ((y & 1u) ? 2567483615u : 0u);
            }
            mti = 0;
        }
        uint32_t y = mt[mti++];
        y ^= y >> 11;
        y ^= (y << 7) & 2636928640u;
        y ^= (y << 15) & 4022730752u;
        y ^= y >> 18;
        return y;
    };
    int arr[64];
    for (int i = 0; i < 64; i++) arr[i] = i;
    for (int i = 63; i >= 1; i--) {
        uint32_t mask = (uint32_t)i;
        mask |= mask >> 1; mask |= mask >> 2; mask |= mask >> 4;
        mask |= mask >> 8; mask |= mask >> 16;
        uint32_t v;
        do { v = genrand() & mask; } while (v > (uint32_t)i);
        int tmp = arr[i]; arr[i] = arr[v]; arr[v] = tmp;
    }
    uint64_t bits = 0;
    for (int d = 0; d < 64; d++)
        if (arr[d] >= 38) bits |= (1ull << d);
    return bits;
}

// ---------------------------------------------------------------------------
// Output-row flag set + compacted list (rows read by the final dot).
// ---------------------------------------------------------------------------
__global__ void flag_kernel(const int* __restrict__ users, const int* __restrict__ items,
                            unsigned char* __restrict__ flag, int B, int U) {
    int i = blockIdx.x * 256 + threadIdx.x;
    if (i < B) flag[users[i]] = 1;
    else if (i < 2 * B) flag[U + items[i - B]] = 1;
}

__global__ void flist_kernel(const unsigned char* __restrict__ flag,
                             int* __restrict__ flist, int* __restrict__ fcount, int n) {
    int i = blockIdx.x * 256 + threadIdx.x;
    if (i < n && flag[i]) {
        int p = atomicAdd(fcount, 1);
        flist[p] = i;
    }
}

// ---------------------------------------------------------------------------
// Per-row CSR build (low-contention: 100k counters, ~10 hits each).
// ---------------------------------------------------------------------------
__global__ void hist_kernel(const int* __restrict__ rows, int* __restrict__ cnt, int e) {
    int i = blockIdx.x * 256 + threadIdx.x;
    if (i < e) atomicAdd(&cnt[rows[i]], 1);
}

__global__ void scan1_kernel(const int* __restrict__ cnt, int* __restrict__ rp,
                             int* __restrict__ bsums, int n) {
    __shared__ int sh[256];
    int t = threadIdx.x;
    int base = blockIdx.x * 1024 + t * 4;
    int v0 = 0, v1 = 0, v2 = 0, v3 = 0;
    if (base + 3 < n) {
        int4 q = *(const int4*)(cnt + base);
        v0 = q.x; v1 = q.y; v2 = q.z; v3 = q.w;
    } else {
        if (base + 0 < n) v0 = cnt[base + 0];
        if (base + 1 < n) v1 = cnt[base + 1];
        if (base + 2 < n) v2 = cnt[base + 2];
        if (base + 3 < n) v3 = cnt[base + 3];
    }
    int total = v0 + v1 + v2 + v3;
    sh[t] = total;
    __syncthreads();
    for (int off = 1; off < 256; off <<= 1) {
        int x = (t >= off) ? sh[t - off] : 0;
        __syncthreads();
        sh[t] += x;
        __syncthreads();
    }
    int excl = sh[t] - total;
    if (base + 0 < n) rp[base + 0] = excl;
    if (base + 1 < n) rp[base + 1] = excl + v0;
    if (base + 2 < n) rp[base + 2] = excl + v0 + v1;
    if (base + 3 < n) rp[base + 3] = excl + v0 + v1 + v2;
    if (t == 255) bsums[blockIdx.x] = sh[255];
}

__global__ void scan2_kernel(int* __restrict__ bsums, int nb) {
    __shared__ int sh[256];
    int t = threadIdx.x;
    int base = t * 4;
    int v[4]; int s = 0;
    #pragma unroll
    for (int j = 0; j < 4; j++) {
        v[j] = (base + j < nb) ? bsums[base + j] : 0;
        s += v[j];
    }
    sh[t] = s;
    __syncthreads();
    for (int off = 1; off < 256; off <<= 1) {
        int x = (t >= off) ? sh[t - off] : 0;
        __syncthreads();
        sh[t] += x;
        __syncthreads();
    }
    int run = sh[t] - s;
    #pragma unroll
    for (int j = 0; j < 4; j++) {
        if (base + j < nb) bsums[base + j] = run;
        run += v[j];
    }
}

__global__ void scan3_kernel(int* __restrict__ rp, const int* __restrict__ bsums,
                             int n, int e_total) {
    int i = blockIdx.x * 256 + threadIdx.x;
    if (i < n) rp[i] += bsums[i >> 10];
    if (i == 0) rp[n] = e_total;
}

// Combined (col,val) uint2 record: one 8B store per edge.
__global__ void scatter_kernel(const int* __restrict__ rows, const int* __restrict__ cols,
                               const float* __restrict__ vals, const int* __restrict__ rp,
                               int* __restrict__ cur, uint2* __restrict__ rec, int e) {
    int i = blockIdx.x * 256 + threadIdx.x;
    if (i >= e) return;
    int rsrc = rows[i];
    int pos = rp[rsrc] + atomicAdd(&cur[rsrc], 1);
    rec[pos] = make_uint2((uint32_t)cols[i], __float_as_uint(vals[i]));
}

// ---------------------------------------------------------------------------
// Per-rating MLP: h = leaky_relu(x @ W1a + c1) @ W2 + b2
// prev = h for all rows; out_acc += h only for flagged rows.
// ---------------------------------------------------------------------------
__global__ __launch_bounds__(256) void mlp_kernel(
    const float* __restrict__ user_emb, const float* __restrict__ item_emb,
    const float* __restrict__ rating_emb, const float* __restrict__ W1,
    const float* __restrict__ b1, const float* __restrict__ W2,
    const float* __restrict__ b2, float* __restrict__ prev,
    float* __restrict__ out_acc, const unsigned char* __restrict__ flag,
    int r, int n_rows, int U) {
    __shared__ float sW1[64 * 64];  // [k][j]
    __shared__ float sW2[64 * 64];  // [k][j]
    __shared__ float sXT[64 * 64];  // [k][i]
    __shared__ float sTT[64 * 64];  // [k][i]
    __shared__ float sc1[64];
    __shared__ float sb2v[64];

    int t = threadIdx.x;
    int row0 = blockIdx.x * 64;
    const float* W1r = W1 + (size_t)r * (128 * 64);
    const float* W2r = W2 + (size_t)r * (64 * 64);

    #pragma unroll
    for (int q = 0; q < 4; q++) {
        int f = t + 256 * q;
        int k = f >> 4, c = (f & 15) * 4;
        *(float4*)(sW1 + k * 64 + c) = *(const float4*)(W1r + k * 64 + c);
        *(float4*)(sW2 + k * 64 + c) = *(const float4*)(W2r + k * 64 + c);
    }
    #pragma unroll
    for (int q = 0; q < 4; q++) {
        int f = t + 256 * q;
        int i = f >> 4, c = (f & 15) * 4;
        int nrow = row0 + i;
        float4 xv = make_float4(0.f, 0.f, 0.f, 0.f);
        if (nrow < n_rows) {
            const float* src = (nrow < U) ? (user_emb + (size_t)nrow * 64)
                                          : (item_emb + (size_t)(nrow - U) * 64);
            xv = *(const float4*)(src + c);
        }
        sXT[(c + 0) * 64 + i] = xv.x;
        sXT[(c + 1) * 64 + i] = xv.y;
        sXT[(c + 2) * 64 + i] = xv.z;
        sXT[(c + 3) * 64 + i] = xv.w;
    }
    if (t < 64) {
        float acc = b1[r * 64 + t];
        for (int k = 0; k < 64; k++)
            acc += rating_emb[r * 64 + k] * W1r[(64 + k) * 64 + t];
        sc1[t] = acc;
    } else if (t < 128) {
        sb2v[t - 64] = b2[r * 64 + (t - 64)];
    }
    __syncthreads();

    int i0 = (t & 15) * 4, j0 = (t >> 4) * 4;
    float acc[4][4];
    #pragma unroll
    for (int a = 0; a < 4; a++)
        #pragma unroll
        for (int b = 0; b < 4; b++) acc[a][b] = sc1[j0 + b];
    for (int k = 0; k < 64; k++) {
        float4 xv = *(const float4*)(sXT + k * 64 + i0);
        float4 wv = *(const float4*)(sW1 + k * 64 + j0);
        float xs[4] = {xv.x, xv.y, xv.z, xv.w};
        float ws[4] = {wv.x, wv.y, wv.z, wv.w};
        #pragma unroll
        for (int a = 0; a < 4; a++)
            #pragma unroll
            for (int b = 0; b < 4; b++) acc[a][b] += xs[a] * ws[b];
    }
    #pragma unroll
    for (int a = 0; a < 4; a++)
        #pragma unroll
        for (int b = 0; b < 4; b++) {
            float v = acc[a][b];
            v = (v >= 0.f) ? v : 0.01f * v;
            sTT[(j0 + b) * 64 + (i0 + a)] = v;
        }
    __syncthreads();

    #pragma unroll
    for (int a = 0; a < 4; a++)
        #pragma unroll
        for (int b = 0; b < 4; b++) acc[a][b] = sb2v[j0 + b];
    for (int k = 0; k < 64; k++) {
        float4 xv = *(const float4*)(sTT + k * 64 + i0);
        float4 wv = *(const float4*)(sW2 + k * 64 + j0);
        float xs[4] = {xv.x, xv.y, xv.z, xv.w};
        float ws[4] = {wv.x, wv.y, wv.z, wv.w};
        #pragma unroll
        for (int a = 0; a < 4; a++)
            #pragma unroll
            for (int b = 0; b < 4; b++) acc[a][b] += xs[a] * ws[b];
    }
    #pragma unroll
    for (int a = 0; a < 4; a++) {
        int nrow = row0 + i0 + a;
        if (nrow < n_rows) {
            float4 hv = make_float4(acc[a][0], acc[a][1], acc[a][2], acc[a][3]);
            *(float4*)(prev + (size_t)nrow * 64 + j0) = hv;
            if (flag[nrow]) {
                float4 ov = *(const float4*)(out_acc + (size_t)nrow * 64 + j0);
                ov.x += hv.x; ov.y += hv.y; ov.z += hv.z; ov.w += hv.w;
                *(float4*)(out_acc + (size_t)nrow * 64 + j0) = ov;
            }
        }
    }
}

// ---------------------------------------------------------------------------
// Gather-SpMM (layers 0/1): one wave per row, lane = dim, 8x unrolled edge
// loop for MLP (memory-level parallelism). out_acc += only for flagged rows.
// ---------------------------------------------------------------------------
__global__ __launch_bounds__(256) void spmm_kernel(
    const float* __restrict__ prev, float* __restrict__ next,
    float* __restrict__ out_acc, const int* __restrict__ rp,
    const uint2* __restrict__ rec, const unsigned char* __restrict__ flag, int n) {
    int wave = (int)((blockIdx.x * (unsigned)blockDim.x + threadIdx.x) >> 6);
    int lane = threadIdx.x & 63;
    if (wave >= n) return;
    int s = rp[wave], e2 = rp[wave + 1];
    float acc = 0.f;
    int e = s;
    for (; e + 7 < e2; e += 8) {
        uint2 r0 = rec[e + 0], r1 = rec[e + 1], r2 = rec[e + 2], r3 = rec[e + 3];
        uint2 r4 = rec[e + 4], r5 = rec[e + 5], r6 = rec[e + 6], r7 = rec[e + 7];
        float p0 = prev[(size_t)r0.x * 64 + lane];
        float p1 = prev[(size_t)r1.x * 64 + lane];
        float p2 = prev[(size_t)r2.x * 64 + lane];
        float p3 = prev[(size_t)r3.x * 64 + lane];
        float p4 = prev[(size_t)r4.x * 64 + lane];
        float p5 = prev[(size_t)r5.x * 64 + lane];
        float p6 = prev[(size_t)r6.x * 64 + lane];
        float p7 = prev[(size_t)r7.x * 64 + lane];
        acc += __uint_as_float(r0.y) * p0; acc += __uint_as_float(r1.y) * p1;
        acc += __uint_as_float(r2.y) * p2; acc += __uint_as_float(r3.y) * p3;
        acc += __uint_as_float(r4.y) * p4; acc += __uint_as_float(r5.y) * p5;
        acc += __uint_as_float(r6.y) * p6; acc += __uint_as_float(r7.y) * p7;
    }
    for (; e + 3 < e2; e += 4) {
        uint2 r0 = rec[e + 0], r1 = rec[e + 1], r2 = rec[e + 2], r3 = rec[e + 3];
        float p0 = prev[(size_t)r0.x * 64 + lane];
        float p1 = prev[(size_t)r1.x * 64 + lane];
        float p2 = prev[(size_t)r2.x * 64 + lane];
        float p3 = prev[(size_t)r3.x * 64 + lane];
        acc += __uint_as_float(r0.y) * p0; acc += __uint_as_float(r1.y) * p1;
        acc += __uint_as_float(r2.y) * p2; acc += __uint_as_float(r3.y) * p3;
    }
    for (; e < e2; e++) {
        uint2 r0 = rec[e];
        acc += __uint_as_float(r0.y) * prev[(size_t)r0.x * 64 + lane];
    }
    next[(size_t)wave * 64 + lane] = acc;
    if (flag[wave]) out_acc[(size_t)wave * 64 + lane] += acc;
}

// ---------------------------------------------------------------------------
// Layer-2 (masked) SpMM: only rows in flist (rows the final dot reads).
// ---------------------------------------------------------------------------
__global__ __launch_bounds__(256) void spmm_masked_kernel(
    const float* __restrict__ prev, float* __restrict__ out_acc,
    const int* __restrict__ rp, const uint2* __restrict__ rec,
    unsigned long long maskbits, const int* __restrict__ flist,
    const int* __restrict__ fcount) {
    int w = (int)((blockIdx.x * (unsigned)blockDim.x + threadIdx.x) >> 6);
    int lane = threadIdx.x & 63;
    if (w >= *fcount) return;
    int row = flist[w];
    int s = rp[row], e2 = rp[row + 1];
    float acc = 0.f;
    int e = s;
    for (; e + 7 < e2; e += 8) {
        uint2 r0 = rec[e + 0], r1 = rec[e + 1], r2 = rec[e + 2], r3 = rec[e + 3];
        uint2 r4 = rec[e + 4], r5 = rec[e + 5], r6 = rec[e + 6], r7 = rec[e + 7];
        float p0 = prev[(size_t)r0.x * 64 + lane];
        float p1 = prev[(size_t)r1.x * 64 + lane];
        float p2 = prev[(size_t)r2.x * 64 + lane];
        float p3 = prev[(size_t)r3.x * 64 + lane];
        float p4 = prev[(size_t)r4.x * 64 + lane];
        float p5 = prev[(size_t)r5.x * 64 + lane];
        float p6 = prev[(size_t)r6.x * 64 + lane];
        float p7 = prev[(size_t)r7.x * 64 + lane];
        acc += __uint_as_float(r0.y) * p0; acc += __uint_as_float(r1.y) * p1;
        acc += __uint_as_float(r2.y) * p2; acc += __uint_as_float(r3.y) * p3;
        acc += __uint_as_float(r4.y) * p4; acc += __uint_as_float(r5.y) * p5;
        acc += __uint_as_float(r6.y) * p6; acc += __uint_as_float(r7.y) * p7;
    }
    for (; e + 3 < e2; e += 4) {
        uint2 r0 = rec[e + 0], r1 = rec[e + 1], r2 = rec[e + 2], r3 = rec[e + 3];
        float p0 = prev[(size_t)r0.x * 64 + lane];
        float p1 = prev[(size_t)r1.x * 64 + lane];
        float p2 = prev[(size_t)r2.x * 64 + lane];
        float p3 = prev[(size_t)r3.x * 64 + lane];
        acc += __uint_as_float(r0.y) * p0; acc += __uint_as_float(r1.y) * p1;
        acc += __uint_as_float(r2.y) * p2; acc += __uint_as_float(r3.y) * p3;
    }
    for (; e < e2; e++) {
        uint2 r0 = rec[e];
        acc += __uint_as_float(r0.y) * prev[(size_t)r0.x * 64 + lane];
    }
    float pv = prev[(size_t)row * 64 + lane];
    float res = ((maskbits >> lane) & 1ull) ? acc : pv;
    out_acc[(size_t)row * 64 + lane] += res;
}

// ---------------------------------------------------------------------------
// Final: out[b] = (1/R^2) * dot(out_acc[users[b]], out_acc[U+items[b]])
// ---------------------------------------------------------------------------
__global__ __launch_bounds__(256) void dot_kernel(
    const float* __restrict__ out_acc, const int* __restrict__ users,
    const int* __restrict__ items, float* __restrict__ out,
    int Bn, int U, float scale) {
    int w = (int)((blockIdx.x * (unsigned)blockDim.x + threadIdx.x) >> 6);
    int lane = threadIdx.x & 63;
    if (w >= Bn) return;
    int u = users[w], it = items[w];
    float a = out_acc[(size_t)u * 64 + lane];
    float c = out_acc[((size_t)(U + it)) * 64 + lane];
    float p = a * c;
    #pragma unroll
    for (int off = 32; off > 0; off >>= 1) p += __shfl_down(p, off);
    if (lane == 0) out[w] = p * scale;
}

// ---------------------------------------------------------------------------
extern "C" void kernel_launch(void* const* d_in, const int* in_sizes, int n_in,
                              void* d_out, int out_size, void* d_ws, size_t ws_size,
                              hipStream_t stream) {
    const int* users = (const int*)d_in[0];
    const int* items = (const int*)d_in[1];
    const float* user_emb = (const float*)d_in[2];
    const float* item_emb = (const float*)d_in[3];
    const float* rating_emb = (const float*)d_in[4];
    const float* W1 = (const float*)d_in[5];
    const float* b1 = (const float*)d_in[6];
    const float* W2 = (const float*)d_in[7];
    const float* b2 = (const float*)d_in[8];
    const int* rows = (const int*)d_in[9];
    const int* cols = (const int*)d_in[10];
    const float* vals = (const float*)d_in[11];
    float* out = (float*)d_out;

    const int Dd = 64;
    int U = in_sizes[2] / Dd;
    int I = in_sizes[3] / Dd;
    int R = in_sizes[4] / Dd;
    int N = U + I;
    int E = in_sizes[9] / R;
    int Bn = in_sizes[0];

    char* p = (char*)d_ws;
    auto carve = [&](size_t bytes) -> char* {
        char* q = p;
        p += (bytes + 255) & ~(size_t)255;
        return q;
    };
    float* out_acc = (float*)carve((size_t)N * 64 * 4);
    float* bufA = (float*)carve((size_t)N * 64 * 4);
    float* bufB = (float*)carve((size_t)N * 64 * 4);
    uint2* rec = (uint2*)carve((size_t)E * 8);
    int* row_ptr = (int*)carve((size_t)(N + 1) * 4);
    int* cntcur = (int*)carve((size_t)2 * N * 4);  // cnt | cur, one memset
    int* cnt = cntcur;
    int* cur = cntcur + N;
    int* bsums = (int*)carve(4096);
    unsigned char* flag = (unsigned char*)carve((size_t)N);
    int* flist = (int*)carve((size_t)2 * Bn * 4);
    int* fcount = (int*)carve(4);

    uint64_t maskbits = compute_mask_bits();

    hipMemsetAsync(out_acc, 0, (size_t)N * 64 * 4, stream);
    hipMemsetAsync(flag, 0, (size_t)N, stream);
    hipMemsetAsync(fcount, 0, 4, stream);

    flag_kernel<<<(2 * Bn + 255) / 256, 256, 0, stream>>>(users, items, flag, Bn, U);
    flist_kernel<<<(N + 255) / 256, 256, 0, stream>>>(flag, flist, fcount, N);

    int NB1 = (N + 1023) / 1024;
    int eblocks = (E + 255) / 256;
    int spmm_blocks = (N + 3) / 4;
    int masked_blocks = (2 * Bn + 3) / 4;  // upper bound on |flist| waves
    for (int r = 0; r < R; r++) {
        const int* rows_r = rows + (size_t)r * E;
        const int* cols_r = cols + (size_t)r * E;
        const float* vals_r = vals + (size_t)r * E;

        hipMemsetAsync(cntcur, 0, (size_t)2 * N * 4, stream);
        hist_kernel<<<eblocks, 256, 0, stream>>>(rows_r, cnt, E);
        scan1_kernel<<<NB1, 256, 0, stream>>>(cnt, row_ptr, bsums, N);
        scan2_kernel<<<1, 256, 0, stream>>>(bsums, NB1);
        scan3_kernel<<<(N + 255) / 256, 256, 0, stream>>>(row_ptr, bsums, N, E);
        scatter_kernel<<<eblocks, 256, 0, stream>>>(rows_r, cols_r, vals_r,
                                                    row_ptr, cur, rec, E);

        mlp_kernel<<<(N + 63) / 64, 256, 0, stream>>>(user_emb, item_emb, rating_emb,
                                                      W1, b1, W2, b2, bufA, out_acc,
                                                      flag, r, N, U);

        spmm_kernel<<<spmm_blocks, 256, 0, stream>>>(bufA, bufB, out_acc, row_ptr,
                                                     rec, flag, N);
        spmm_kernel<<<spmm_blocks, 256, 0, stream>>>(bufB, bufA, out_acc, row_ptr,
                                                     rec, flag, N);
        spmm_masked_kernel<<<masked_blocks, 256, 0, stream>>>(bufA, out_acc, row_ptr,
                                                              rec, maskbits,
                                                              flist, fcount);
    }

    float scale = 1.0f / (float)(R * R);
    dot_kernel<<<(Bn * 64 + 255) / 256, 256, 0, stream>>>(out_acc, users, items, out,
                                                          Bn, U, scale);
}

// Round 6
// 1319.426 us; speedup vs baseline: 4.6064x; 1.1332x over previous
//
#include <hip/hip_runtime.h>
#include <hip/hip_bf16.h>
#include <cstdint>
#include <cstddef>

// ---------------------------------------------------------------------------
// Host-side reproduction of np.random.RandomState(2).permutation(64):
// MT19937 init_genrand(2), Fisher-Yates with numpy random_interval
// (mask+rejection). Mask bit d = (perm[d] >= 38).
// ---------------------------------------------------------------------------
static uint64_t compute_mask_bits() {
    uint32_t mt[624];
    mt[0] = 2u;
    for (int i = 1; i < 624; i++)
        mt[i] = 1812433253u * (mt[i - 1] ^ (mt[i - 1] >> 30)) + (uint32_t)i;
    int mti = 624;
    auto genrand = [&]() -> uint32_t {
        if (mti >= 624) {
            for (int k = 0; k < 624; k++) {
                uint32_t y = (mt[k] & 0x80000000u) | (mt[(k + 1) % 624] & 0x7fffffffu);
                mt[k] = mt[(k + 397) % 624] ^ (y >> 1) ^ ((y & 1u) ? 2567483615u : 0u);
            }
            mti = 0;
        }
        uint32_t y = mt[mti++];
        y ^= y >> 11;
        y ^= (y << 7) & 2636928640u;
        y ^= (y << 15) & 4022730752u;
        y ^= y >> 18;
        return y;
    };
    int arr[64];
    for (int i = 0; i < 64; i++) arr[i] = i;
    for (int i = 63; i >= 1; i--) {
        uint32_t mask = (uint32_t)i;
        mask |= mask >> 1; mask |= mask >> 2; mask |= mask >> 4;
        mask |= mask >> 8; mask |= mask >> 16;
        uint32_t v;
        do { v = genrand() & mask; } while (v > (uint32_t)i);
        int tmp = arr[i]; arr[i] = arr[v]; arr[v] = tmp;
    }
    uint64_t bits = 0;
    for (int d = 0; d < 64; d++)
        if (arr[d] >= 38) bits |= (1ull << d);
    return bits;
}

// ---------------------------------------------------------------------------
// Output-row flag set + compacted list (rows read by the final dot).
// ---------------------------------------------------------------------------
__global__ void flag_kernel(const int* __restrict__ users, const int* __restrict__ items,
                            unsigned char* __restrict__ flag, int B, int U) {
    int i = blockIdx.x * 256 + threadIdx.x;
    if (i < B) flag[users[i]] = 1;
    else if (i < 2 * B) flag[U + items[i - B]] = 1;
}

__global__ void flist_kernel(const unsigned char* __restrict__ flag,
                             int* __restrict__ flist, int* __restrict__ fcount, int n) {
    int i = blockIdx.x * 256 + threadIdx.x;
    if (i < n && flag[i]) {
        int p = atomicAdd(fcount, 1);
        flist[p] = i;
    }
}

// ---------------------------------------------------------------------------
// Per-row CSR build. hist also captures each edge's within-row rank (the
// atomicAdd return) so the scatter pass needs no far atomic.
// ---------------------------------------------------------------------------
__global__ void hist_kernel(const int* __restrict__ rows, int* __restrict__ cnt,
                            int* __restrict__ rank, int e) {
    int i = blockIdx.x * 256 + threadIdx.x;
    if (i < e) rank[i] = atomicAdd(&cnt[rows[i]], 1);
}

__global__ void scan1_kernel(const int* __restrict__ cnt, int* __restrict__ rp,
                             int* __restrict__ bsums, int n) {
    __shared__ int sh[256];
    int t = threadIdx.x;
    int base = blockIdx.x * 1024 + t * 4;
    int v0 = 0, v1 = 0, v2 = 0, v3 = 0;
    if (base + 3 < n) {
        int4 q = *(const int4*)(cnt + base);
        v0 = q.x; v1 = q.y; v2 = q.z; v3 = q.w;
    } else {
        if (base + 0 < n) v0 = cnt[base + 0];
        if (base + 1 < n) v1 = cnt[base + 1];
        if (base + 2 < n) v2 = cnt[base + 2];
        if (base + 3 < n) v3 = cnt[base + 3];
    }
    int total = v0 + v1 + v2 + v3;
    sh[t] = total;
    __syncthreads();
    for (int off = 1; off < 256; off <<= 1) {
        int x = (t >= off) ? sh[t - off] : 0;
        __syncthreads();
        sh[t] += x;
        __syncthreads();
    }
    int excl = sh[t] - total;
    if (base + 0 < n) rp[base + 0] = excl;
    if (base + 1 < n) rp[base + 1] = excl + v0;
    if (base + 2 < n) rp[base + 2] = excl + v0 + v1;
    if (base + 3 < n) rp[base + 3] = excl + v0 + v1 + v2;
    if (t == 255) bsums[blockIdx.x] = sh[255];
}

__global__ void scan2_kernel(int* __restrict__ bsums, int nb) {
    __shared__ int sh[256];
    int t = threadIdx.x;
    int base = t * 4;
    int v[4]; int s = 0;
    #pragma unroll
    for (int j = 0; j < 4; j++) {
        v[j] = (base + j < nb) ? bsums[base + j] : 0;
        s += v[j];
    }
    sh[t] = s;
    __syncthreads();
    for (int off = 1; off < 256; off <<= 1) {
        int x = (t >= off) ? sh[t - off] : 0;
        __syncthreads();
        sh[t] += x;
        __syncthreads();
    }
    int run = sh[t] - s;
    #pragma unroll
    for (int j = 0; j < 4; j++) {
        if (base + j < nb) bsums[base + j] = run;
        run += v[j];
    }
}

__global__ void scan3_kernel(int* __restrict__ rp, const int* __restrict__ bsums,
                             int n, int e_total) {
    int i = blockIdx.x * 256 + threadIdx.x;
    if (i < n) rp[i] += bsums[i >> 10];
    if (i == 0) rp[n] = e_total;
}

// Atomic-free scatter: pos = rp[row] + rank[i]; one 8B combined record store.
__global__ void scatter_kernel(const int* __restrict__ rows, const int* __restrict__ cols,
                               const float* __restrict__ vals, const int* __restrict__ rp,
                               const int* __restrict__ rank, uint2* __restrict__ rec, int e) {
    int i = blockIdx.x * 256 + threadIdx.x;
    if (i >= e) return;
    int pos = rp[rows[i]] + rank[i];
    rec[pos] = make_uint2((uint32_t)cols[i], __float_as_uint(vals[i]));
}

// ---------------------------------------------------------------------------
// Per-rating MLP: h = leaky_relu(x @ W1a + c1) @ W2 + b2
// prev = h for all rows; out_acc += h only for flagged rows.
// ---------------------------------------------------------------------------
__global__ __launch_bounds__(256) void mlp_kernel(
    const float* __restrict__ user_emb, const float* __restrict__ item_emb,
    const float* __restrict__ rating_emb, const float* __restrict__ W1,
    const float* __restrict__ b1, const float* __restrict__ W2,
    const float* __restrict__ b2, float* __restrict__ prev,
    float* __restrict__ out_acc, const unsigned char* __restrict__ flag,
    int r, int n_rows, int U) {
    __shared__ float sW1[64 * 64];  // [k][j]
    __shared__ float sW2[64 * 64];  // [k][j]
    __shared__ float sXT[64 * 64];  // [k][i]
    __shared__ float sTT[64 * 64];  // [k][i]
    __shared__ float sc1[64];
    __shared__ float sb2v[64];

    int t = threadIdx.x;
    int row0 = blockIdx.x * 64;
    const float* W1r = W1 + (size_t)r * (128 * 64);
    const float* W2r = W2 + (size_t)r * (64 * 64);

    #pragma unroll
    for (int q = 0; q < 4; q++) {
        int f = t + 256 * q;
        int k = f >> 4, c = (f & 15) * 4;
        *(float4*)(sW1 + k * 64 + c) = *(const float4*)(W1r + k * 64 + c);
        *(float4*)(sW2 + k * 64 + c) = *(const float4*)(W2r + k * 64 + c);
    }
    #pragma unroll
    for (int q = 0; q < 4; q++) {
        int f = t + 256 * q;
        int i = f >> 4, c = (f & 15) * 4;
        int nrow = row0 + i;
        float4 xv = make_float4(0.f, 0.f, 0.f, 0.f);
        if (nrow < n_rows) {
            const float* src = (nrow < U) ? (user_emb + (size_t)nrow * 64)
                                          : (item_emb + (size_t)(nrow - U) * 64);
            xv = *(const float4*)(src + c);
        }
        sXT[(c + 0) * 64 + i] = xv.x;
        sXT[(c + 1) * 64 + i] = xv.y;
        sXT[(c + 2) * 64 + i] = xv.z;
        sXT[(c + 3) * 64 + i] = xv.w;
    }
    if (t < 64) {
        float acc = b1[r * 64 + t];
        for (int k = 0; k < 64; k++)
            acc += rating_emb[r * 64 + k] * W1r[(64 + k) * 64 + t];
        sc1[t] = acc;
    } else if (t < 128) {
        sb2v[t - 64] = b2[r * 64 + (t - 64)];
    }
    __syncthreads();

    int i0 = (t & 15) * 4, j0 = (t >> 4) * 4;
    float acc[4][4];
    #pragma unroll
    for (int a = 0; a < 4; a++)
        #pragma unroll
        for (int b = 0; b < 4; b++) acc[a][b] = sc1[j0 + b];
    for (int k = 0; k < 64; k++) {
        float4 xv = *(const float4*)(sXT + k * 64 + i0);
        float4 wv = *(const float4*)(sW1 + k * 64 + j0);
        float xs[4] = {xv.x, xv.y, xv.z, xv.w};
        float ws[4] = {wv.x, wv.y, wv.z, wv.w};
        #pragma unroll
        for (int a = 0; a < 4; a++)
            #pragma unroll
            for (int b = 0; b < 4; b++) acc[a][b] += xs[a] * ws[b];
    }
    #pragma unroll
    for (int a = 0; a < 4; a++)
        #pragma unroll
        for (int b = 0; b < 4; b++) {
            float v = acc[a][b];
            v = (v >= 0.f) ? v : 0.01f * v;
            sTT[(j0 + b) * 64 + (i0 + a)] = v;
        }
    __syncthreads();

    #pragma unroll
    for (int a = 0; a < 4; a++)
        #pragma unroll
        for (int b = 0; b < 4; b++) acc[a][b] = sb2v[j0 + b];
    for (int k = 0; k < 64; k++) {
        float4 xv = *(const float4*)(sTT + k * 64 + i0);
        float4 wv = *(const float4*)(sW2 + k * 64 + j0);
        float xs[4] = {xv.x, xv.y, xv.z, xv.w};
        float ws[4] = {wv.x, wv.y, wv.z, wv.w};
        #pragma unroll
        for (int a = 0; a < 4; a++)
            #pragma unroll
            for (int b = 0; b < 4; b++) acc[a][b] += xs[a] * ws[b];
    }
    #pragma unroll
    for (int a = 0; a < 4; a++) {
        int nrow = row0 + i0 + a;
        if (nrow < n_rows) {
            float4 hv = make_float4(acc[a][0], acc[a][1], acc[a][2], acc[a][3]);
            *(float4*)(prev + (size_t)nrow * 64 + j0) = hv;
            if (flag[nrow]) {
                float4 ov = *(const float4*)(out_acc + (size_t)nrow * 64 + j0);
                ov.x += hv.x; ov.y += hv.y; ov.z += hv.z; ov.w += hv.w;
                *(float4*)(out_acc + (size_t)nrow * 64 + j0) = ov;
            }
        }
    }
}

// ---------------------------------------------------------------------------
// Gather-SpMM (layers 0/1): wave = 1 row; 4 edge-groups x 16 lanes x float4.
// One gather instruction covers 4 edges; 2x unroll = 8 edges in flight.
// Cross-group reduce via shfl_xor(16/32). out_acc += for flagged rows.
// ---------------------------------------------------------------------------
__global__ __launch_bounds__(256) void spmm_kernel(
    const float* __restrict__ prev, float* __restrict__ next,
    float* __restrict__ out_acc, const int* __restrict__ rp,
    const uint2* __restrict__ rec, const unsigned char* __restrict__ flag, int n) {
    int wave = (int)((blockIdx.x * (unsigned)blockDim.x + threadIdx.x) >> 6);
    int lane = threadIdx.x & 63;
    if (wave >= n) return;
    int sub = lane >> 4;      // edge group 0..3
    int dl = lane & 15;       // dims [dl*4, dl*4+4)
    int s = rp[wave], e2 = rp[wave + 1];
    float ax = 0.f, ay = 0.f, az = 0.f, aw = 0.f;
    int e = s + sub;
    for (; e + 4 < e2; e += 8) {
        uint2 r0 = rec[e];
        uint2 r1 = rec[e + 4];
        float4 p0 = *(const float4*)(prev + (size_t)r0.x * 64 + dl * 4);
        float4 p1 = *(const float4*)(prev + (size_t)r1.x * 64 + dl * 4);
        float v0 = __uint_as_float(r0.y), v1 = __uint_as_float(r1.y);
        ax += v0 * p0.x; ay += v0 * p0.y; az += v0 * p0.z; aw += v0 * p0.w;
        ax += v1 * p1.x; ay += v1 * p1.y; az += v1 * p1.z; aw += v1 * p1.w;
    }
    if (e < e2) {
        uint2 r0 = rec[e];
        float4 p0 = *(const float4*)(prev + (size_t)r0.x * 64 + dl * 4);
        float v0 = __uint_as_float(r0.y);
        ax += v0 * p0.x; ay += v0 * p0.y; az += v0 * p0.z; aw += v0 * p0.w;
    }
    ax += __shfl_xor(ax, 16); ay += __shfl_xor(ay, 16);
    az += __shfl_xor(az, 16); aw += __shfl_xor(aw, 16);
    ax += __shfl_xor(ax, 32); ay += __shfl_xor(ay, 32);
    az += __shfl_xor(az, 32); aw += __shfl_xor(aw, 32);
    if (sub == 0) {
        *(float4*)(next + (size_t)wave * 64 + dl * 4) = make_float4(ax, ay, az, aw);
    } else if (sub == 1 && flag[wave]) {
        float* o = out_acc + (size_t)wave * 64 + dl * 4;
        float4 ov = *(const float4*)o;
        ov.x += ax; ov.y += ay; ov.z += az; ov.w += aw;
        *(float4*)o = ov;
    }
}

// ---------------------------------------------------------------------------
// Layer-2 (masked) SpMM: only rows in flist. Same float4-lane layout.
// ---------------------------------------------------------------------------
__global__ __launch_bounds__(256) void spmm_masked_kernel(
    const float* __restrict__ prev, float* __restrict__ out_acc,
    const int* __restrict__ rp, const uint2* __restrict__ rec,
    unsigned long long maskbits, const int* __restrict__ flist,
    const int* __restrict__ fcount) {
    int w = (int)((blockIdx.x * (unsigned)blockDim.x + threadIdx.x) >> 6);
    int lane = threadIdx.x & 63;
    if (w >= *fcount) return;
    int sub = lane >> 4;
    int dl = lane & 15;
    int row = flist[w];
    int s = rp[row], e2 = rp[row + 1];
    float ax = 0.f, ay = 0.f, az = 0.f, aw = 0.f;
    int e = s + sub;
    for (; e + 4 < e2; e += 8) {
        uint2 r0 = rec[e];
        uint2 r1 = rec[e + 4];
        float4 p0 = *(const float4*)(prev + (size_t)r0.x * 64 + dl * 4);
        float4 p1 = *(const float4*)(prev + (size_t)r1.x * 64 + dl * 4);
        float v0 = __uint_as_float(r0.y), v1 = __uint_as_float(r1.y);
        ax += v0 * p0.x; ay += v0 * p0.y; az += v0 * p0.z; aw += v0 * p0.w;
        ax += v1 * p1.x; ay += v1 * p1.y; az += v1 * p1.z; aw += v1 * p1.w;
    }
    if (e < e2) {
        uint2 r0 = rec[e];
        float4 p0 = *(const float4*)(prev + (size_t)r0.x * 64 + dl * 4);
        float v0 = __uint_as_float(r0.y);
        ax += v0 * p0.x; ay += v0 * p0.y; az += v0 * p0.z; aw += v0 * p0.w;
    }
    ax += __shfl_xor(ax, 16); ay += __shfl_xor(ay, 16);
    az += __shfl_xor(az, 16); aw += __shfl_xor(aw, 16);
    ax += __shfl_xor(ax, 32); ay += __shfl_xor(ay, 32);
    az += __shfl_xor(az, 32); aw += __shfl_xor(aw, 32);
    if (sub == 0) {
        const float* pv = prev + (size_t)row * 64 + dl * 4;
        float4 pvv = *(const float4*)pv;
        float rx = ((maskbits >> (dl * 4 + 0)) & 1ull) ? ax : pvv.x;
        float ry = ((maskbits >> (dl * 4 + 1)) & 1ull) ? ay : pvv.y;
        float rz = ((maskbits >> (dl * 4 + 2)) & 1ull) ? az : pvv.z;
        float rw = ((maskbits >> (dl * 4 + 3)) & 1ull) ? aw : pvv.w;
        float* o = out_acc + (size_t)row * 64 + dl * 4;
        float4 ov = *(const float4*)o;
        ov.x += rx; ov.y += ry; ov.z += rz; ov.w += rw;
        *(float4*)o = ov;
    }
}

// ---------------------------------------------------------------------------
// Final: out[b] = (1/R^2) * dot(out_acc[users[b]], out_acc[U+items[b]])
// ---------------------------------------------------------------------------
__global__ __launch_bounds__(256) void dot_kernel(
    const float* __restrict__ out_acc, const int* __restrict__ users,
    const int* __restrict__ items, float* __restrict__ out,
    int Bn, int U, float scale) {
    int w = (int)((blockIdx.x * (unsigned)blockDim.x + threadIdx.x) >> 6);
    int lane = threadIdx.x & 63;
    if (w >= Bn) return;
    int u = users[w], it = items[w];
    float a = out_acc[(size_t)u * 64 + lane];
    float c = out_acc[((size_t)(U + it)) * 64 + lane];
    float p = a * c;
    #pragma unroll
    for (int off = 32; off > 0; off >>= 1) p += __shfl_down(p, off);
    if (lane == 0) out[w] = p * scale;
}

// ---------------------------------------------------------------------------
extern "C" void kernel_launch(void* const* d_in, const int* in_sizes, int n_in,
                              void* d_out, int out_size, void* d_ws, size_t ws_size,
                              hipStream_t stream) {
    const int* users = (const int*)d_in[0];
    const int* items = (const int*)d_in[1];
    const float* user_emb = (const float*)d_in[2];
    const float* item_emb = (const float*)d_in[3];
    const float* rating_emb = (const float*)d_in[4];
    const float* W1 = (const float*)d_in[5];
    const float* b1 = (const float*)d_in[6];
    const float* W2 = (const float*)d_in[7];
    const float* b2 = (const float*)d_in[8];
    const int* rows = (const int*)d_in[9];
    const int* cols = (const int*)d_in[10];
    const float* vals = (const float*)d_in[11];
    float* out = (float*)d_out;

    const int Dd = 64;
    int U = in_sizes[2] / Dd;
    int I = in_sizes[3] / Dd;
    int R = in_sizes[4] / Dd;
    int N = U + I;
    int E = in_sizes[9] / R;
    int Bn = in_sizes[0];

    char* p = (char*)d_ws;
    auto carve = [&](size_t bytes) -> char* {
        char* q = p;
        p += (bytes + 255) & ~(size_t)255;
        return q;
    };
    float* out_acc = (float*)carve((size_t)N * 64 * 4);
    float* bufA = (float*)carve((size_t)N * 64 * 4);
    float* bufB = (float*)carve((size_t)N * 64 * 4);
    uint2* rec = (uint2*)carve((size_t)E * 8);
    int* rank = (int*)carve((size_t)E * 4);
    int* row_ptr = (int*)carve((size_t)(N + 1) * 4);
    int* cnt = (int*)carve((size_t)N * 4);
    int* bsums = (int*)carve(4096);
    unsigned char* flag = (unsigned char*)carve((size_t)N);
    int* flist = (int*)carve((size_t)2 * Bn * 4);
    int* fcount = (int*)carve(4);

    uint64_t maskbits = compute_mask_bits();

    hipMemsetAsync(out_acc, 0, (size_t)N * 64 * 4, stream);
    hipMemsetAsync(flag, 0, (size_t)N, stream);
    hipMemsetAsync(fcount, 0, 4, stream);

    flag_kernel<<<(2 * Bn + 255) / 256, 256, 0, stream>>>(users, items, flag, Bn, U);
    flist_kernel<<<(N + 255) / 256, 256, 0, stream>>>(flag, flist, fcount, N);

    int NB1 = (N + 1023) / 1024;
    int eblocks = (E + 255) / 256;
    int spmm_blocks = (N + 3) / 4;
    int masked_blocks = (2 * Bn + 3) / 4;  // upper bound on |flist| waves
    for (int r = 0; r < R; r++) {
        const int* rows_r = rows + (size_t)r * E;
        const int* cols_r = cols + (size_t)r * E;
        const float* vals_r = vals + (size_t)r * E;

        hipMemsetAsync(cnt, 0, (size_t)N * 4, stream);
        hist_kernel<<<eblocks, 256, 0, stream>>>(rows_r, cnt, rank, E);
        scan1_kernel<<<NB1, 256, 0, stream>>>(cnt, row_ptr, bsums, N);
        scan2_kernel<<<1, 256, 0, stream>>>(bsums, NB1);
        scan3_kernel<<<(N + 255) / 256, 256, 0, stream>>>(row_ptr, bsums, N, E);
        scatter_kernel<<<eblocks, 256, 0, stream>>>(rows_r, cols_r, vals_r,
                                                    row_ptr, rank, rec, E);

        mlp_kernel<<<(N + 63) / 64, 256, 0, stream>>>(user_emb, item_emb, rating_emb,
                                                      W1, b1, W2, b2, bufA, out_acc,
                                                      flag, r, N, U);

        spmm_kernel<<<spmm_blocks, 256, 0, stream>>>(bufA, bufB, out_acc, row_ptr,
                                                     rec, flag, N);
        spmm_kernel<<<spmm_blocks, 256, 0, stream>>>(bufB, bufA, out_acc, row_ptr,
                                                     rec, flag, N);
        spmm_masked_kernel<<<masked_blocks, 256, 0, stream>>>(bufA, out_acc, row_ptr,
                                                              rec, maskbits,
                                                              flist, fcount);
    }

    float scale = 1.0f / (float)(R * R);
    dot_kernel<<<(Bn * 64 + 255) / 256, 256, 0, stream>>>(out_acc, users, items, out,
                                                          Bn, U, scale);
}

// Round 7
// 1198.794 us; speedup vs baseline: 5.0699x; 1.1006x over previous
//
#include <hip/hip_runtime.h>
#include <hip/hip_bf16.h>
#include <cstdint>
#include <cstddef>

// ---------------------------------------------------------------------------
// Host-side reproduction of np.random.RandomState(2).permutation(64):
// MT19937 init_genrand(2), Fisher-Yates with numpy random_interval
// (mask+rejection). Mask bit d = (perm[d] >= 38).
// ---------------------------------------------------------------------------
static uint64_t compute_mask_bits() {
    uint32_t mt[624];
    mt[0] = 2u;
    for (int i = 1; i < 624; i++)
        mt[i] = 1812433253u * (mt[i - 1] ^ (mt[i - 1] >> 30)) + (uint32_t)i;
    int mti = 624;
    auto genrand = [&]() -> uint32_t {
        if (mti >= 624) {
            for (int k = 0; k < 624; k++) {
                uint32_t y = (mt[k] & 0x80000000u) | (mt[(k + 1) % 624] & 0x7fffffffu);
                mt[k] = mt[(k + 397) % 624] ^ (y >> 1) ^ ((y & 1u) ? 2567483615u : 0u);
            }
            mti = 0;
        }
        uint32_t y = mt[mti++];
        y ^= y >> 11;
        y ^= (y << 7) & 2636928640u;
        y ^= (y << 15) & 4022730752u;
        y ^= y >> 18;
        return y;
    };
    int arr[64];
    for (int i = 0; i < 64; i++) arr[i] = i;
    for (int i = 63; i >= 1; i--) {
        uint32_t mask = (uint32_t)i;
        mask |= mask >> 1; mask |= mask >> 2; mask |= mask >> 4;
        mask |= mask >> 8; mask |= mask >> 16;
        uint32_t v;
        do { v = genrand() & mask; } while (v > (uint32_t)i);
        int tmp = arr[i]; arr[i] = arr[v]; arr[v] = tmp;
    }
    uint64_t bits = 0;
    for (int d = 0; d < 64; d++)
        if (arr[d] >= 38) bits |= (1ull << d);
    return bits;
}

// ---------------------------------------------------------------------------
// Output-row flag set + compacted list (rows read by the final dot).
// ---------------------------------------------------------------------------
__global__ void flag_kernel(const int* __restrict__ users, const int* __restrict__ items,
                            unsigned char* __restrict__ flag, int B, int U) {
    int i = blockIdx.x * 256 + threadIdx.x;
    if (i < B) flag[users[i]] = 1;
    else if (i < 2 * B) flag[U + items[i - B]] = 1;
}

__global__ void flist_kernel(const unsigned char* __restrict__ flag,
                             int* __restrict__ flist, int* __restrict__ fcount, int n) {
    int i = blockIdx.x * 256 + threadIdx.x;
    if (i < n && flag[i]) {
        int p = atomicAdd(fcount, 1);
        flist[p] = i;
    }
}

// ---------------------------------------------------------------------------
// Per-rating constant c1[r][j] = b1[r][j] + sum_k e_r[k] * W1[r][64+k][j].
// ---------------------------------------------------------------------------
__global__ void c1_kernel(const float* __restrict__ rating_emb, const float* __restrict__ W1,
                          const float* __restrict__ b1, float* __restrict__ c1_all) {
    int r = blockIdx.x;
    int t = threadIdx.x;  // 64 threads
    const float* W1r = W1 + (size_t)r * (128 * 64);
    float acc = b1[r * 64 + t];
    for (int k = 0; k < 64; k++)
        acc += rating_emb[r * 64 + k] * W1r[(64 + k) * 64 + t];
    c1_all[r * 64 + t] = acc;
}

// ---------------------------------------------------------------------------
// Batched CSR build over all R ratings at once: cnt[5N] counters (low
// contention), rank = within-row order captured from atomicAdd return.
// ---------------------------------------------------------------------------
__global__ void hist_all_kernel(const int* __restrict__ rows, int* __restrict__ cnt,
                                int* __restrict__ rank, int etot, int E, int N) {
    int i = blockIdx.x * 256 + threadIdx.x;
    if (i >= etot) return;
    int r = i / E;
    rank[i] = atomicAdd(&cnt[r * N + rows[i]], 1);
}

__global__ void scan1_kernel(const int* __restrict__ cnt, int* __restrict__ rp,
                             int* __restrict__ bsums, int n) {
    __shared__ int sh[256];
    int t = threadIdx.x;
    int base = blockIdx.x * 1024 + t * 4;
    int v0 = 0, v1 = 0, v2 = 0, v3 = 0;
    if (base + 3 < n) {
        int4 q = *(const int4*)(cnt + base);
        v0 = q.x; v1 = q.y; v2 = q.z; v3 = q.w;
    } else {
        if (base + 0 < n) v0 = cnt[base + 0];
        if (base + 1 < n) v1 = cnt[base + 1];
        if (base + 2 < n) v2 = cnt[base + 2];
        if (base + 3 < n) v3 = cnt[base + 3];
    }
    int total = v0 + v1 + v2 + v3;
    sh[t] = total;
    __syncthreads();
    for (int off = 1; off < 256; off <<= 1) {
        int x = (t >= off) ? sh[t - off] : 0;
        __syncthreads();
        sh[t] += x;
        __syncthreads();
    }
    int excl = sh[t] - total;
    if (base + 0 < n) rp[base + 0] = excl;
    if (base + 1 < n) rp[base + 1] = excl + v0;
    if (base + 2 < n) rp[base + 2] = excl + v0 + v1;
    if (base + 3 < n) rp[base + 3] = excl + v0 + v1 + v2;
    if (t == 255) bsums[blockIdx.x] = sh[255];
}

__global__ void scan2_kernel(int* __restrict__ bsums, int nb) {
    __shared__ int sh[256];
    int t = threadIdx.x;
    int base = t * 4;
    int v[4]; int s = 0;
    #pragma unroll
    for (int j = 0; j < 4; j++) {
        v[j] = (base + j < nb) ? bsums[base + j] : 0;
        s += v[j];
    }
    sh[t] = s;
    __syncthreads();
    for (int off = 1; off < 256; off <<= 1) {
        int x = (t >= off) ? sh[t - off] : 0;
        __syncthreads();
        sh[t] += x;
        __syncthreads();
    }
    int run = sh[t] - s;
    #pragma unroll
    for (int j = 0; j < 4; j++) {
        if (base + j < nb) bsums[base + j] = run;
        run += v[j];
    }
}

__global__ void scan3_kernel(int* __restrict__ rp, const int* __restrict__ bsums,
                             int n, int e_total) {
    int i = blockIdx.x * 256 + threadIdx.x;
    if (i < n) rp[i] += bsums[i >> 10];
    if (i == 0) rp[n] = e_total;
}

// Atomic-free per-rating scatter; rp is pre-offset by r*N, positions rebased
// by ebase = r*E so rec stays E-sized.
__global__ void scatter_kernel(const int* __restrict__ rows, const int* __restrict__ cols,
                               const float* __restrict__ vals, const int* __restrict__ rp,
                               const int* __restrict__ rank, uint2* __restrict__ rec,
                               int e, int ebase) {
    int i = blockIdx.x * 256 + threadIdx.x;
    if (i >= e) return;
    int pos = rp[rows[i]] - ebase + rank[i];
    rec[pos] = make_uint2((uint32_t)cols[i], __float_as_uint(vals[i]));
}

// ---------------------------------------------------------------------------
// Per-rating MLP: h = leaky_relu(x @ W1a + c1) @ W2 + b2
// LDS: one W tile + one X/T tile (reused) = 33 KB -> 4 blocks/CU.
// [k][i] tiles use a 16B-group XOR swizzle (g ^ (k&15)) -> conflict-free
// staging writes, T writes, and GEMM reads.
// prev = h for all rows; out_acc += h only for flagged rows.
// ---------------------------------------------------------------------------
__global__ __launch_bounds__(256) void mlp_kernel(
    const float* __restrict__ user_emb, const float* __restrict__ item_emb,
    const float* __restrict__ W1, const float* __restrict__ W2,
    const float* __restrict__ c1_all, const float* __restrict__ b2,
    float* __restrict__ prev, float* __restrict__ out_acc,
    const unsigned char* __restrict__ flag, int r, int n_rows, int U) {
    __shared__ float sW[64 * 64];   // [k][j], linear
    __shared__ float sX[64 * 64];   // [k][i], group-swizzled; reused for T
    __shared__ float sc1[64];
    __shared__ float sb2v[64];

    int t = threadIdx.x;
    int row0 = blockIdx.x * 64;
    const float* W1r = W1 + (size_t)r * (128 * 64);
    const float* W2r = W2 + (size_t)r * (64 * 64);

    // stage W1 (x-part rows 0..63), linear float4
    #pragma unroll
    for (int q = 0; q < 4; q++) {
        int f = t + 256 * q;
        int k = f >> 4, c = (f & 15) * 4;
        *(float4*)(sW + k * 64 + c) = *(const float4*)(W1r + k * 64 + c);
    }
    // stage X^T swizzled: lane handles row i = f&63, dims c..c+3
    #pragma unroll
    for (int q = 0; q < 4; q++) {
        int f = t + 256 * q;
        int i = f & 63;
        int c = (f >> 6) * 4;
        int nrow = row0 + i;
        float4 xv = make_float4(0.f, 0.f, 0.f, 0.f);
        if (nrow < n_rows) {
            const float* src = (nrow < U) ? (user_emb + (size_t)nrow * 64)
                                          : (item_emb + (size_t)(nrow - U) * 64);
            xv = *(const float4*)(src + c);
        }
        int gi = i >> 2, w = i & 3;
        sX[(c + 0) * 64 + 4 * (gi ^ ((c + 0) & 15)) + w] = xv.x;
        sX[(c + 1) * 64 + 4 * (gi ^ ((c + 1) & 15)) + w] = xv.y;
        sX[(c + 2) * 64 + 4 * (gi ^ ((c + 2) & 15)) + w] = xv.z;
        sX[(c + 3) * 64 + 4 * (gi ^ ((c + 3) & 15)) + w] = xv.w;
    }
    if (t < 64) sc1[t] = c1_all[r * 64 + t];
    else if (t < 128) sb2v[t - 64] = b2[r * 64 + (t - 64)];
    __syncthreads();

    int gi = t & 15;
    int i0 = gi * 4, j0 = (t >> 4) * 4;
    float acc[4][4];
    #pragma unroll
    for (int a = 0; a < 4; a++)
        #pragma unroll
        for (int b = 0; b < 4; b++) acc[a][b] = sc1[j0 + b];
    for (int k = 0; k < 64; k++) {
        float4 xv = *(const float4*)(sX + k * 64 + 4 * (gi ^ (k & 15)));
        float4 wv = *(const float4*)(sW + k * 64 + j0);
        float xs[4] = {xv.x, xv.y, xv.z, xv.w};
        float ws[4] = {wv.x, wv.y, wv.z, wv.w};
        #pragma unroll
        for (int a = 0; a < 4; a++)
            #pragma unroll
            for (int b = 0; b < 4; b++) acc[a][b] += xs[a] * ws[b];
    }
    __syncthreads();  // all GEMM1 reads done; safe to overwrite sX/sW

    // write T = leaky_relu(acc) into sX (swizzled), restage sW = W2
    #pragma unroll
    for (int b = 0; b < 4; b++) {
        int k = j0 + b;
        float4 tv;
        tv.x = (acc[0][b] >= 0.f) ? acc[0][b] : 0.01f * acc[0][b];
        tv.y = (acc[1][b] >= 0.f) ? acc[1][b] : 0.01f * acc[1][b];
        tv.z = (acc[2][b] >= 0.f) ? acc[2][b] : 0.01f * acc[2][b];
        tv.w = (acc[3][b] >= 0.f) ? acc[3][b] : 0.01f * acc[3][b];
        *(float4*)(sX + k * 64 + 4 * (gi ^ (k & 15))) = tv;
    }
    #pragma unroll
    for (int q = 0; q < 4; q++) {
        int f = t + 256 * q;
        int k = f >> 4, c = (f & 15) * 4;
        *(float4*)(sW + k * 64 + c) = *(const float4*)(W2r + k * 64 + c);
    }
    __syncthreads();

    #pragma unroll
    for (int a = 0; a < 4; a++)
        #pragma unroll
        for (int b = 0; b < 4; b++) acc[a][b] = sb2v[j0 + b];
    for (int k = 0; k < 64; k++) {
        float4 xv = *(const float4*)(sX + k * 64 + 4 * (gi ^ (k & 15)));
        float4 wv = *(const float4*)(sW + k * 64 + j0);
        float xs[4] = {xv.x, xv.y, xv.z, xv.w};
        float ws[4] = {wv.x, wv.y, wv.z, wv.w};
        #pragma unroll
        for (int a = 0; a < 4; a++)
            #pragma unroll
            for (int b = 0; b < 4; b++) acc[a][b] += xs[a] * ws[b];
    }
    #pragma unroll
    for (int a = 0; a < 4; a++) {
        int nrow = row0 + i0 + a;
        if (nrow < n_rows) {
            float4 hv = make_float4(acc[a][0], acc[a][1], acc[a][2], acc[a][3]);
            *(float4*)(prev + (size_t)nrow * 64 + j0) = hv;
            if (flag[nrow]) {
                float4 ov = *(const float4*)(out_acc + (size_t)nrow * 64 + j0);
                ov.x += hv.x; ov.y += hv.y; ov.z += hv.z; ov.w += hv.w;
                *(float4*)(out_acc + (size_t)nrow * 64 + j0) = ov;
            }
        }
    }
}

// ---------------------------------------------------------------------------
// Gather-SpMM (layers 0/1): wave = 1 row; 4 edge-groups x 16 lanes x float4.
// rp is pre-offset by r*N; positions rebased by ebase = r*E.
// ---------------------------------------------------------------------------
__global__ __launch_bounds__(256) void spmm_kernel(
    const float* __restrict__ prev, float* __restrict__ next,
    float* __restrict__ out_acc, const int* __restrict__ rp,
    const uint2* __restrict__ rec, const unsigned char* __restrict__ flag,
    int n, int ebase) {
    int wave = (int)((blockIdx.x * (unsigned)blockDim.x + threadIdx.x) >> 6);
    int lane = threadIdx.x & 63;
    if (wave >= n) return;
    int sub = lane >> 4;      // edge group 0..3
    int dl = lane & 15;       // dims [dl*4, dl*4+4)
    int s = rp[wave] - ebase, e2 = rp[wave + 1] - ebase;
    float ax = 0.f, ay = 0.f, az = 0.f, aw = 0.f;
    int e = s + sub;
    for (; e + 4 < e2; e += 8) {
        uint2 r0 = rec[e];
        uint2 r1 = rec[e + 4];
        float4 p0 = *(const float4*)(prev + (size_t)r0.x * 64 + dl * 4);
        float4 p1 = *(const float4*)(prev + (size_t)r1.x * 64 + dl * 4);
        float v0 = __uint_as_float(r0.y), v1 = __uint_as_float(r1.y);
        ax += v0 * p0.x; ay += v0 * p0.y; az += v0 * p0.z; aw += v0 * p0.w;
        ax += v1 * p1.x; ay += v1 * p1.y; az += v1 * p1.z; aw += v1 * p1.w;
    }
    if (e < e2) {
        uint2 r0 = rec[e];
        float4 p0 = *(const float4*)(prev + (size_t)r0.x * 64 + dl * 4);
        float v0 = __uint_as_float(r0.y);
        ax += v0 * p0.x; ay += v0 * p0.y; az += v0 * p0.z; aw += v0 * p0.w;
    }
    ax += __shfl_xor(ax, 16); ay += __shfl_xor(ay, 16);
    az += __shfl_xor(az, 16); aw += __shfl_xor(aw, 16);
    ax += __shfl_xor(ax, 32); ay += __shfl_xor(ay, 32);
    az += __shfl_xor(az, 32); aw += __shfl_xor(aw, 32);
    if (sub == 0) {
        *(float4*)(next + (size_t)wave * 64 + dl * 4) = make_float4(ax, ay, az, aw);
    } else if (sub == 1 && flag[wave]) {
        float* o = out_acc + (size_t)wave * 64 + dl * 4;
        float4 ov = *(const float4*)o;
        ov.x += ax; ov.y += ay; ov.z += az; ov.w += aw;
        *(float4*)o = ov;
    }
}

// ---------------------------------------------------------------------------
// Layer-2 (masked) SpMM: only rows in flist. Same float4-lane layout.
// ---------------------------------------------------------------------------
__global__ __launch_bounds__(256) void spmm_masked_kernel(
    const float* __restrict__ prev, float* __restrict__ out_acc,
    const int* __restrict__ rp, const uint2* __restrict__ rec,
    unsigned long long maskbits, const int* __restrict__ flist,
    const int* __restrict__ fcount, int ebase) {
    int w = (int)((blockIdx.x * (unsigned)blockDim.x + threadIdx.x) >> 6);
    int lane = threadIdx.x & 63;
    if (w >= *fcount) return;
    int sub = lane >> 4;
    int dl = lane & 15;
    int row = flist[w];
    int s = rp[row] - ebase, e2 = rp[row + 1] - ebase;
    float ax = 0.f, ay = 0.f, az = 0.f, aw = 0.f;
    int e = s + sub;
    for (; e + 4 < e2; e += 8) {
        uint2 r0 = rec[e];
        uint2 r1 = rec[e + 4];
        float4 p0 = *(const float4*)(prev + (size_t)r0.x * 64 + dl * 4);
        float4 p1 = *(const float4*)(prev + (size_t)r1.x * 64 + dl * 4);
        float v0 = __uint_as_float(r0.y), v1 = __uint_as_float(r1.y);
        ax += v0 * p0.x; ay += v0 * p0.y; az += v0 * p0.z; aw += v0 * p0.w;
        ax += v1 * p1.x; ay += v1 * p1.y; az += v1 * p1.z; aw += v1 * p1.w;
    }
    if (e < e2) {
        uint2 r0 = rec[e];
        float4 p0 = *(const float4*)(prev + (size_t)r0.x * 64 + dl * 4);
        float v0 = __uint_as_float(r0.y);
        ax += v0 * p0.x; ay += v0 * p0.y; az += v0 * p0.z; aw += v0 * p0.w;
    }
    ax += __shfl_xor(ax, 16); ay += __shfl_xor(ay, 16);
    az += __shfl_xor(az, 16); aw += __shfl_xor(aw, 16);
    ax += __shfl_xor(ax, 32); ay += __shfl_xor(ay, 32);
    az += __shfl_xor(az, 32); aw += __shfl_xor(aw, 32);
    if (sub == 0) {
        const float* pv = prev + (size_t)row * 64 + dl * 4;
        float4 pvv = *(const float4*)pv;
        float rx = ((maskbits >> (dl * 4 + 0)) & 1ull) ? ax : pvv.x;
        float ry = ((maskbits >> (dl * 4 + 1)) & 1ull) ? ay : pvv.y;
        float rz = ((maskbits >> (dl * 4 + 2)) & 1ull) ? az : pvv.z;
        float rw = ((maskbits >> (dl * 4 + 3)) & 1ull) ? aw : pvv.w;
        float* o = out_acc + (size_t)row * 64 + dl * 4;
        float4 ov = *(const float4*)o;
        ov.x += rx; ov.y += ry; ov.z += rz; ov.w += rw;
        *(float4*)o = ov;
    }
}

// ---------------------------------------------------------------------------
// Final: out[b] = (1/R^2) * dot(out_acc[users[b]], out_acc[U+items[b]])
// ---------------------------------------------------------------------------
__global__ __launch_bounds__(256) void dot_kernel(
    const float* __restrict__ out_acc, const int* __restrict__ users,
    const int* __restrict__ items, float* __restrict__ out,
    int Bn, int U, float scale) {
    int w = (int)((blockIdx.x * (unsigned)blockDim.x + threadIdx.x) >> 6);
    int lane = threadIdx.x & 63;
    if (w >= Bn) return;
    int u = users[w], it = items[w];
    float a = out_acc[(size_t)u * 64 + lane];
    float c = out_acc[((size_t)(U + it)) * 64 + lane];
    float p = a * c;
    #pragma unroll
    for (int off = 32; off > 0; off >>= 1) p += __shfl_down(p, off);
    if (lane == 0) out[w] = p * scale;
}

// ---------------------------------------------------------------------------
extern "C" void kernel_launch(void* const* d_in, const int* in_sizes, int n_in,
                              void* d_out, int out_size, void* d_ws, size_t ws_size,
                              hipStream_t stream) {
    const int* users = (const int*)d_in[0];
    const int* items = (const int*)d_in[1];
    const float* user_emb = (const float*)d_in[2];
    const float* item_emb = (const float*)d_in[3];
    const float* rating_emb = (const float*)d_in[4];
    const float* W1 = (const float*)d_in[5];
    const float* b1 = (const float*)d_in[6];
    const float* W2 = (const float*)d_in[7];
    const float* b2 = (const float*)d_in[8];
    const int* rows = (const int*)d_in[9];
    const int* cols = (const int*)d_in[10];
    const float* vals = (const float*)d_in[11];
    float* out = (float*)d_out;

    const int Dd = 64;
    int U = in_sizes[2] / Dd;
    int I = in_sizes[3] / Dd;
    int R = in_sizes[4] / Dd;
    int N = U + I;
    int E = in_sizes[9] / R;
    int Bn = in_sizes[0];
    int NR = N * R;
    int Etot = E * R;

    char* p = (char*)d_ws;
    auto carve = [&](size_t bytes) -> char* {
        char* q = p;
        p += (bytes + 255) & ~(size_t)255;
        return q;
    };
    float* out_acc = (float*)carve((size_t)N * 64 * 4);
    float* bufA = (float*)carve((size_t)N * 64 * 4);
    float* bufB = (float*)carve((size_t)N * 64 * 4);
    uint2* rec = (uint2*)carve((size_t)E * 8);
    int* rank = (int*)carve((size_t)Etot * 4);
    int* row_ptr = (int*)carve((size_t)(NR + 1) * 4);
    int* cnt = (int*)carve((size_t)NR * 4);
    int* bsums = (int*)carve(4096);
    float* c1_all = (float*)carve((size_t)R * 64 * 4);
    unsigned char* flag = (unsigned char*)carve((size_t)N);
    int* flist = (int*)carve((size_t)2 * Bn * 4);
    int* fcount = (int*)carve(4);

    uint64_t maskbits = compute_mask_bits();

    hipMemsetAsync(out_acc, 0, (size_t)N * 64 * 4, stream);
    hipMemsetAsync(flag, 0, (size_t)N, stream);
    hipMemsetAsync(fcount, 0, 4, stream);
    hipMemsetAsync(cnt, 0, (size_t)NR * 4, stream);

    flag_kernel<<<(2 * Bn + 255) / 256, 256, 0, stream>>>(users, items, flag, Bn, U);
    flist_kernel<<<(N + 255) / 256, 256, 0, stream>>>(flag, flist, fcount, N);
    c1_kernel<<<R, 64, 0, stream>>>(rating_emb, W1, b1, c1_all);

    // batched CSR build (hist + scan) over all ratings
    hist_all_kernel<<<(Etot + 255) / 256, 256, 0, stream>>>(rows, cnt, rank, Etot, E, N);
    int NB1 = (NR + 1023) / 1024;
    scan1_kernel<<<NB1, 256, 0, stream>>>(cnt, row_ptr, bsums, NR);
    scan2_kernel<<<1, 256, 0, stream>>>(bsums, NB1);
    scan3_kernel<<<(NR + 255) / 256, 256, 0, stream>>>(row_ptr, bsums, NR, Etot);

    int eblocks = (E + 255) / 256;
    int spmm_blocks = (N + 3) / 4;
    int masked_blocks = (2 * Bn + 3) / 4;  // upper bound on |flist| waves
    for (int r = 0; r < R; r++) {
        const int* rows_r = rows + (size_t)r * E;
        const int* cols_r = cols + (size_t)r * E;
        const float* vals_r = vals + (size_t)r * E;
        const int* rp_r = row_ptr + (size_t)r * N;
        int ebase = r * E;

        scatter_kernel<<<eblocks, 256, 0, stream>>>(rows_r, cols_r, vals_r, rp_r,
                                                    rank + (size_t)r * E, rec, E, ebase);

        mlp_kernel<<<(N + 63) / 64, 256, 0, stream>>>(user_emb, item_emb, W1, W2,
                                                      c1_all, b2, bufA, out_acc,
                                                      flag, r, N, U);

        spmm_kernel<<<spmm_blocks, 256, 0, stream>>>(bufA, bufB, out_acc, rp_r,
                                                     rec, flag, N, ebase);
        spmm_kernel<<<spmm_blocks, 256, 0, stream>>>(bufB, bufA, out_acc, rp_r,
                                                     rec, flag, N, ebase);
        spmm_masked_kernel<<<masked_blocks, 256, 0, stream>>>(bufA, out_acc, rp_r,
                                                              rec, maskbits,
                                                              flist, fcount, ebase);
    }

    float scale = 1.0f / (float)(R * R);
    dot_kernel<<<(Bn * 64 + 255) / 256, 256, 0, stream>>>(out_acc, users, items, out,
                                                          Bn, U, scale);
}